// Round 13
// baseline (334.337 us; speedup 1.0000x reference)
//
#include <hip/hip_runtime.h>
#include <math.h>

#define HW 2304       // 48*48
#define NC 256        // channels
#define NPIX 2500     // 50*50 padded grid
#define NPIXP 2560    // padded row stride for channel-first buffers / Gram
#define MATSZ 65536   // 256*256
#define NS_ITERS 5    // iter0 folded + 4 GEMM iterations
#define NSLAB 6
#define KSLAB 384     // 2304/6
#define PMSZ (2560 * 256)  // pixel-major buffer elems per batch
#define GSZ ((u64)NPIXP * NPIXP)

typedef unsigned long long u64;
typedef unsigned short ushortt;
typedef __attribute__((ext_vector_type(8))) short bhalf8;
typedef __attribute__((ext_vector_type(4))) float f32x4;

// ---------------- means + trace (f64): snorm[m] = 1.25*trace/256 ----------------
__global__ void mean_kernel(const float* __restrict__ c, const float* __restrict__ s,
                            double* __restrict__ mean, double* __restrict__ snorm) {
  int ch = blockIdx.x, m = blockIdx.y;
  const float* src = (m < 2 ? c + m * (NC * HW) : s + (m - 2) * (NC * HW)) + ch * HW;
  double acc = 0.0, acc2 = 0.0;
  for (int n = threadIdx.x; n < HW; n += 64) {
    double v = (double)src[n];
    acc += v; acc2 += v * v;
  }
  for (int o = 32; o > 0; o >>= 1) {
    acc += __shfl_down(acc, o);
    acc2 += __shfl_down(acc2, o);
  }
  if (threadIdx.x == 0) {
    mean[m * NC + ch] = acc / (double)HW;
    double diag = acc2 - acc * acc / (double)HW;   // = sum x^2 - HW*mu^2
    atomicAdd(&snorm[m], 1.25 * diag / 256.0);
  }
}

// ---------------- covariance partials: raw sum(x*y), 64x64 tile, 4x4/thread ----------------
__launch_bounds__(256)
__global__ void cov_part(const float* __restrict__ c, const float* __restrict__ s,
                         float* __restrict__ covp) {
  int z = blockIdx.z;
  int m = z / NSLAB, slab = z % NSLAB;
  const float* src = (m < 2 ? c + m * (NC * HW) : s + (m - 2) * (NC * HW));
  int i0 = blockIdx.y * 64, j0 = blockIdx.x * 64;
  int kb = slab * KSLAB;
  __shared__ float As[16][64], Bs[16][64];
  int tx = threadIdx.x, ty = threadIdx.y;
  int tid = ty * 16 + tx;
  int li = tid >> 2;
  int lk4 = tid & 3;
  float acc[4][4] = {};
  for (int kc = 0; kc < KSLAB; kc += 16) {
    __syncthreads();
    float4 va = *(const float4*)&src[(u64)(i0 + li) * HW + kb + kc + lk4 * 4];
    float4 vb = *(const float4*)&src[(u64)(j0 + li) * HW + kb + kc + lk4 * 4];
    As[lk4 * 4 + 0][li] = va.x; As[lk4 * 4 + 1][li] = va.y;
    As[lk4 * 4 + 2][li] = va.z; As[lk4 * 4 + 3][li] = va.w;
    Bs[lk4 * 4 + 0][li] = vb.x; Bs[lk4 * 4 + 1][li] = vb.y;
    Bs[lk4 * 4 + 2][li] = vb.z; Bs[lk4 * 4 + 3][li] = vb.w;
    __syncthreads();
    #pragma unroll
    for (int kk = 0; kk < 16; ++kk) {
      float4 a = *(const float4*)&As[kk][ty * 4];
      float4 b = *(const float4*)&Bs[kk][tx * 4];
      float av[4] = {a.x, a.y, a.z, a.w};
      float bv[4] = {b.x, b.y, b.z, b.w};
      #pragma unroll
      for (int i = 0; i < 4; ++i)
        #pragma unroll
        for (int j = 0; j < 4; ++j) acc[i][j] += av[i] * bv[j];
    }
  }
  float* Cp = covp + (u64)z * MATSZ;
  #pragma unroll
  for (int i = 0; i < 4; ++i) {
    float4 v = make_float4(acc[i][0], acc[i][1], acc[i][2], acc[i][3]);
    *(float4*)&Cp[(i0 + ty * 4 + i) * NC + j0 + tx * 4] = v;
  }
}

// grid(256,4), block 256. Y0 = (cov)/s; Z1 = T0 = 1.5I - 0.5*Y0 (NS iter0 folded).
__global__ void cov_reduce(const float* __restrict__ covp, const double* __restrict__ mean,
                           const double* __restrict__ snorm,
                           float* __restrict__ Y0, float* __restrict__ Z1) {
  int m = blockIdx.y;
  int row = blockIdx.x, col = threadIdx.x;
  int e = row * 256 + col;
  float v = 0.0f;
  #pragma unroll
  for (int slab = 0; slab < NSLAB; ++slab)
    v += covp[(u64)(m * NSLAB + slab) * MATSZ + e];
  double mi = mean[m * NC + row], mj = mean[m * NC + col];
  float res = (float)((double)v - (double)HW * mi * mj);
  float inv = (float)(1.0 / snorm[m]);
  float y0 = res * inv;
  Y0[m * MATSZ + e] = y0;
  Z1[m * MATSZ + e] = ((row == col) ? 1.5f : 0.0f) - 0.5f * y0;
}

// ---------------- Newton-Schulz GEMMs (256x256x256, f32) ----------------
__launch_bounds__(256)
__global__ void ns_gemm_Y(const float* __restrict__ Y0, const float* __restrict__ T0,
                          float* __restrict__ Y1) {
  int m = blockIdx.z;
  const float* A = Y0 + m * MATSZ;
  const float* B = T0 + m * MATSZ;
  float* Cp = Y1 + m * MATSZ;
  int m0 = blockIdx.y * 32, n0 = blockIdx.x * 32;
  __shared__ float As[32][33], Bs[32][33];
  int tx = threadIdx.x, ty = threadIdx.y;
  int tid = ty * 16 + tx;
  float acc[2][2] = {};
  for (int k0 = 0; k0 < 256; k0 += 32) {
    __syncthreads();
    #pragma unroll
    for (int l = 0; l < 4; ++l) {
      int idx = tid + l * 256;
      int r = idx >> 5, cc = idx & 31;
      As[r][cc] = A[(m0 + r) * NC + k0 + cc];
      Bs[r][cc] = B[(k0 + r) * NC + n0 + cc];
    }
    __syncthreads();
    #pragma unroll
    for (int kk = 0; kk < 32; ++kk) {
      float a0 = As[ty][kk], a1 = As[ty + 16][kk];
      float b0 = Bs[kk][tx], b1 = Bs[kk][tx + 16];
      acc[0][0] += a0 * b0; acc[0][1] += a0 * b1;
      acc[1][0] += a1 * b0; acc[1][1] += a1 * b1;
    }
  }
  #pragma unroll
  for (int i = 0; i < 2; ++i)
    #pragma unroll
    for (int j = 0; j < 2; ++j)
      Cp[(m0 + ty + 16 * i) * NC + n0 + tx + 16 * j] = acc[i][j];
}

__launch_bounds__(256)
__global__ void ns_gemm_T(const float* __restrict__ Zc, const float* __restrict__ Yc,
                          float* __restrict__ T) {
  int m = blockIdx.z;
  const float* A = Zc + m * MATSZ;
  const float* B = Yc + m * MATSZ;
  int m0 = blockIdx.y * 32, n0 = blockIdx.x * 32;
  __shared__ float As[32][33], Bs[32][33];
  int tx = threadIdx.x, ty = threadIdx.y;
  int tid = ty * 16 + tx;
  float acc[2][2] = {};
  for (int k0 = 0; k0 < 256; k0 += 32) {
    __syncthreads();
    #pragma unroll
    for (int l = 0; l < 4; ++l) {
      int idx = tid + l * 256;
      int r = idx >> 5, cc = idx & 31;
      As[r][cc] = A[(m0 + r) * NC + k0 + cc];
      Bs[r][cc] = B[(k0 + r) * NC + n0 + cc];
    }
    __syncthreads();
    #pragma unroll
    for (int kk = 0; kk < 32; ++kk) {
      float a0 = As[ty][kk], a1 = As[ty + 16][kk];
      float b0 = Bs[kk][tx], b1 = Bs[kk][tx + 16];
      acc[0][0] += a0 * b0; acc[0][1] += a0 * b1;
      acc[1][0] += a1 * b0; acc[1][1] += a1 * b1;
    }
  }
  float* Cp = T + m * MATSZ;
  #pragma unroll
  for (int i = 0; i < 2; ++i)
    #pragma unroll
    for (int j = 0; j < 2; ++j) {
      int row = m0 + ty + 16 * i, col = n0 + tx + 16 * j;
      Cp[row * NC + col] = (row == col ? 1.5f : 0.0f) - 0.5f * acc[i][j];
    }
}

__launch_bounds__(256)
__global__ void ns_gemm_YZ(const float* __restrict__ Yc, const float* __restrict__ Zc,
                           const float* __restrict__ T,
                           float* __restrict__ Yn, float* __restrict__ Zn) {
  int z = blockIdx.z;
  int m = z & 3;
  bool isY = (z < 4);
  const float* A = isY ? (Yc + m * MATSZ) : (T + m * MATSZ);
  const float* B = isY ? (T + m * MATSZ) : (Zc + m * MATSZ);
  float* Cp = isY ? (Yn + m * MATSZ) : (Zn + m * MATSZ);
  int m0 = blockIdx.y * 32, n0 = blockIdx.x * 32;
  __shared__ float As[32][33], Bs[32][33];
  int tx = threadIdx.x, ty = threadIdx.y;
  int tid = ty * 16 + tx;
  float acc[2][2] = {};
  for (int k0 = 0; k0 < 256; k0 += 32) {
    __syncthreads();
    #pragma unroll
    for (int l = 0; l < 4; ++l) {
      int idx = tid + l * 256;
      int r = idx >> 5, cc = idx & 31;
      As[r][cc] = A[(m0 + r) * NC + k0 + cc];
      Bs[r][cc] = B[(k0 + r) * NC + n0 + cc];
    }
    __syncthreads();
    #pragma unroll
    for (int kk = 0; kk < 32; ++kk) {
      float a0 = As[ty][kk], a1 = As[ty + 16][kk];
      float b0 = Bs[kk][tx], b1 = Bs[kk][tx + 16];
      acc[0][0] += a0 * b0; acc[0][1] += a0 * b1;
      acc[1][0] += a1 * b0; acc[1][1] += a1 * b1;
    }
  }
  #pragma unroll
  for (int i = 0; i < 2; ++i)
    #pragma unroll
    for (int j = 0; j < 2; ++j)
      Cp[(m0 + ty + 16 * i) * NC + n0 + tx + 16 * j] = acc[i][j];
}

// ---------------- whitening apply: 64x64 tile, 4x4/thread, float4 LDS ----------------
__launch_bounds__(256)
__global__ void whiten_kernel(const float* __restrict__ c, const float* __restrict__ s,
                              const float* __restrict__ Zf,
                              const double* __restrict__ snorm, const double* __restrict__ mean,
                              float* __restrict__ padC_cf, float* __restrict__ padS_cf,
                              float* __restrict__ padS_cl) {
  int mat = blockIdx.z;
  const float* src = (mat < 2 ? c + mat * (NC * HW) : s + (mat - 2) * (NC * HW));
  const float* A = Zf + mat * MATSZ;
  const double* mn = mean + mat * NC;
  float wscale = (float)(1.0 / sqrt(snorm[mat]));
  int m0 = blockIdx.y * 64, n0 = blockIdx.x * 64;
  __shared__ float As[16][68], Bs[16][68];
  int tid = threadIdx.x;
  int tx = tid & 15, ty = tid >> 4;
  int li = tid >> 2, lk4 = tid & 3;
  int kr = tid >> 4, p4 = (tid & 15) * 4;
  float acc[4][4] = {};
  for (int kc = 0; kc < 256; kc += 16) {
    __syncthreads();
    float4 va = *(const float4*)&A[(u64)(m0 + li) * NC + kc + lk4 * 4];
    As[lk4 * 4 + 0][li] = va.x; As[lk4 * 4 + 1][li] = va.y;
    As[lk4 * 4 + 2][li] = va.z; As[lk4 * 4 + 3][li] = va.w;
    float mk = (float)mn[kc + kr];
    float4 vb = *(const float4*)&src[(u64)(kc + kr) * HW + n0 + p4];
    vb.x -= mk; vb.y -= mk; vb.z -= mk; vb.w -= mk;
    *(float4*)&Bs[kr][p4] = vb;
    __syncthreads();
    #pragma unroll
    for (int kk = 0; kk < 16; ++kk) {
      float4 a = *(const float4*)&As[kk][ty * 4];
      float4 b = *(const float4*)&Bs[kk][tx * 4];
      float av[4] = {a.x, a.y, a.z, a.w};
      float bv[4] = {b.x, b.y, b.z, b.w};
      #pragma unroll
      for (int i = 0; i < 4; ++i)
        #pragma unroll
        for (int j = 0; j < 4; ++j) acc[i][j] += av[i] * bv[j];
    }
  }
  #pragma unroll
  for (int i = 0; i < 4; ++i) {
    int row = m0 + ty * 4 + i;
    #pragma unroll
    for (int j = 0; j < 4; ++j) {
      int n = n0 + tx * 4 + j;
      float v = acc[i][j] * wscale;
      int y = n / 48, x = n % 48;
      int ppos = (y + 1) * 50 + (x + 1);
      if (mat < 2) {
        padC_cf[(u64)mat * (NC * NPIXP) + row * NPIXP + ppos] = v;
      } else {
        padS_cf[(u64)(mat - 2) * (NC * NPIXP) + row * NPIXP + ppos] = v;
        padS_cl[(u64)(mat - 2) * (NPIX * NC) + ppos * NC + row] = v;
      }
    }
  }
}

// ---------------- transpose + bf16 split + per-pixel sumsq (style) ----------------
__launch_bounds__(256)
__global__ void tsplit_kernel(const float* __restrict__ padC_cf, const float* __restrict__ padS_cf,
                              ushortt* __restrict__ padCk_hi, ushortt* __restrict__ padCk_lo,
                              ushortt* __restrict__ padSk_hi, ushortt* __restrict__ padSk_lo,
                              float* __restrict__ ssq) {
  int p0 = blockIdx.x * 64;
  int by = blockIdx.y;
  const float* src = (by < 2) ? padC_cf + (u64)by * (NC * NPIXP)
                              : padS_cf + (u64)(by - 2) * (NC * NPIXP);
  ushortt* dhi = (by < 2) ? padCk_hi + (u64)by * PMSZ : padSk_hi + (u64)(by - 2) * PMSZ;
  ushortt* dlo = (by < 2) ? padCk_lo + (u64)by * PMSZ : padSk_lo + (u64)(by - 2) * PMSZ;
  __shared__ float Tk[64][68];
  int tid = threadIdx.x;
  int rr = tid >> 4, c4 = (tid & 15) * 4;
  int p = tid >> 2, kg = (tid & 3) * 16;
  float sq = 0.0f;
  for (int ks = 0; ks < 256; ks += 64) {
    __syncthreads();
    #pragma unroll
    for (int it = 0; it < 4; ++it) {
      int r = rr + it * 16;
      *(float4*)&Tk[r][c4] = *(const float4*)&src[(u64)(ks + r) * NPIXP + p0 + c4];
    }
    __syncthreads();
    __align__(16) ushortt h[16], lo[16];
    #pragma unroll
    for (int e = 0; e < 16; ++e) {
      float v = Tk[kg + e][p];
      sq += v * v;
      unsigned bb = __float_as_uint(v);
      unsigned hu = (bb + 0x7FFFu + ((bb >> 16) & 1u)) >> 16;
      float hf = __uint_as_float(hu << 16);
      float rres = v - hf;
      unsigned lb = __float_as_uint(rres);
      unsigned lu = (lb + 0x7FFFu + ((lb >> 16) & 1u)) >> 16;
      h[e] = (ushortt)hu;
      lo[e] = (ushortt)lu;
    }
    u64 off = (u64)(p0 + p) * 256 + ks + kg;
    *(uint4*)&dhi[off] = *(const uint4*)&h[0];
    *(uint4*)&dhi[off + 8] = *(const uint4*)&h[8];
    *(uint4*)&dlo[off] = *(const uint4*)&lo[0];
    *(uint4*)&dlo[off + 8] = *(const uint4*)&lo[8];
  }
  sq += __shfl_down(sq, 2);
  sq += __shfl_down(sq, 1);
  if (by >= 2 && (tid & 3) == 0 && (p0 + p) < NPIX)
    ssq[(u64)(by - 2) * NPIX + p0 + p] = sq;
}

// ---------------- MFMA Gram: G[p][q] = sum_k C[p][k]*S[q][k], split-bf16, z=batch -------
__launch_bounds__(256)
__global__ void gram_mfma(const ushortt* __restrict__ Ah_b, const ushortt* __restrict__ Al_b,
                          const ushortt* __restrict__ Bh_b, const ushortt* __restrict__ Bl_b,
                          float* __restrict__ Gb) {
  int bz = blockIdx.z;
  const ushortt* Ah_g = Ah_b + (u64)bz * PMSZ;
  const ushortt* Al_g = Al_b + (u64)bz * PMSZ;
  const ushortt* Bh_g = Bh_b + (u64)bz * PMSZ;
  const ushortt* Bl_g = Bl_b + (u64)bz * PMSZ;
  float* G = Gb + (u64)bz * GSZ;
  __shared__ ushortt As_hi[128 * 32], As_lo[128 * 32], Bs_hi[64 * 32], Bs_lo[64 * 32];
  int tid = threadIdx.x;
  int wv = tid >> 6, l = tid & 63, lr = l & 15, lk = l >> 4;
  int p0 = blockIdx.x * 128, q0 = blockIdx.y * 64;
  int arow = tid >> 2;
  int apart = (tid & 3) * 8;
  const ushortt* pAh0 = Ah_g + (u64)(p0 + arow) * 256 + apart;
  const ushortt* pAh1 = Ah_g + (u64)(p0 + arow + 64) * 256 + apart;
  const ushortt* pAl0 = Al_g + (u64)(p0 + arow) * 256 + apart;
  const ushortt* pAl1 = Al_g + (u64)(p0 + arow + 64) * 256 + apart;
  const ushortt* pBh  = Bh_g + (u64)(q0 + arow) * 256 + apart;
  const ushortt* pBl  = Bl_g + (u64)(q0 + arow) * 256 + apart;
  float4 rAh0 = *(const float4*)pAh0;
  float4 rAh1 = *(const float4*)pAh1;
  float4 rAl0 = *(const float4*)pAl0;
  float4 rAl1 = *(const float4*)pAl1;
  float4 rBh  = *(const float4*)pBh;
  float4 rBl  = *(const float4*)pBl;
  f32x4 acc[2][4];
  #pragma unroll
  for (int a = 0; a < 2; ++a)
    #pragma unroll
    for (int b = 0; b < 4; ++b)
      #pragma unroll
      for (int e = 0; e < 4; ++e) acc[a][b][e] = 0.0f;
  for (int k0 = 0; k0 < 256; k0 += 32) {
    __syncthreads();
    *(float4*)&As_hi[arow * 32 + apart] = rAh0;
    *(float4*)&As_hi[(arow + 64) * 32 + apart] = rAh1;
    *(float4*)&As_lo[arow * 32 + apart] = rAl0;
    *(float4*)&As_lo[(arow + 64) * 32 + apart] = rAl1;
    *(float4*)&Bs_hi[arow * 32 + apart] = rBh;
    *(float4*)&Bs_lo[arow * 32 + apart] = rBl;
    __syncthreads();
    if (k0 + 32 < 256) {
      rAh0 = *(const float4*)(pAh0 + k0 + 32);
      rAh1 = *(const float4*)(pAh1 + k0 + 32);
      rAl0 = *(const float4*)(pAl0 + k0 + 32);
      rAl1 = *(const float4*)(pAl1 + k0 + 32);
      rBh  = *(const float4*)(pBh + k0 + 32);
      rBl  = *(const float4*)(pBl + k0 + 32);
    }
    bhalf8 Ah[2], Al[2], Bh[4], Bl[4];
    #pragma unroll
    for (int a = 0; a < 2; ++a) {
      int off = (wv * 32 + a * 16 + lr) * 32 + lk * 8;
      Ah[a] = *(const bhalf8*)&As_hi[off];
      Al[a] = *(const bhalf8*)&As_lo[off];
    }
    #pragma unroll
    for (int b = 0; b < 4; ++b) {
      int off = (b * 16 + lr) * 32 + lk * 8;
      Bh[b] = *(const bhalf8*)&Bs_hi[off];
      Bl[b] = *(const bhalf8*)&Bs_lo[off];
    }
    #pragma unroll
    for (int a = 0; a < 2; ++a)
      #pragma unroll
      for (int b = 0; b < 4; ++b) {
        acc[a][b] = __builtin_amdgcn_mfma_f32_16x16x32_bf16(Ah[a], Bh[b], acc[a][b], 0, 0, 0);
        acc[a][b] = __builtin_amdgcn_mfma_f32_16x16x32_bf16(Ah[a], Bl[b], acc[a][b], 0, 0, 0);
        acc[a][b] = __builtin_amdgcn_mfma_f32_16x16x32_bf16(Al[a], Bh[b], acc[a][b], 0, 0, 0);
      }
  }
  #pragma unroll
  for (int a = 0; a < 2; ++a)
    #pragma unroll
    for (int b = 0; b < 4; ++b)
      #pragma unroll
      for (int r = 0; r < 4; ++r) {
        int p = p0 + wv * 32 + a * 16 + lk * 4 + r;
        int q = q0 + b * 16 + lr;
        G[(u64)p * NPIXP + q] = acc[a][b][r];
      }
}

// ---------------- scoremax: diagonal-tiled stencil + rknorm + argmax ----------------
// Block = (tile j, diagonal c = ys-y, batch). ny=4 outputs share ny+2 bands (1.5 vs 3.0
// bands/output). grid(12, 95, 2), block 256.
__launch_bounds__(256)
__global__ void scoremax_kernel(const float* __restrict__ Gb, const float* __restrict__ ssq,
                                u64* __restrict__ rmax) {
  int j = blockIdx.x, cidx = blockIdx.y, b = blockIdx.z;
  int c = cidx - 47;                      // ys - y
  int y_lo = c < 0 ? -c : 0;
  int y_hi = c < 0 ? 47 : 47 - c;
  int yt0 = y_lo + j * 4;
  if (yt0 > y_hi) return;
  int ny = min(4, y_hi - yt0 + 1);
  int nb = ny + 2;
  const float* G = Gb + (u64)b * GSZ;
  const float* sq = ssq + (u64)b * NPIX;
  __shared__ float bands[6][2500];
  __shared__ float ssqb[6][52];
  __shared__ float sc[48][52];
  __shared__ float rkl[48];
  int tid = threadIdx.x;
  for (int e = tid; e < nb * 2500; e += 256) {
    int bi = e / 2500, rem = e - bi * 2500;
    int u = rem / 50, v = rem - u * 50;
    int a = yt0 + bi;                     // row band a, col band a+c
    bands[bi][rem] = G[(u64)(a * 50 + u) * NPIXP + (a + c) * 50 + v];
  }
  for (int e = tid; e < nb * 50; e += 256) {
    int bi = e / 50, v = e - bi * 50;
    ssqb[bi][v] = sq[(yt0 + bi + c) * 50 + v];
  }
  __syncthreads();
  for (int jj = 0; jj < ny; ++jj) {
    int y = yt0 + jj, ys = y + c;
    #pragma unroll
    for (int k = 0; k < 9; ++k) {
      int idx = tid + k * 256;
      int x = idx / 48, xs = idx - x * 48;
      float v = 0.0f;
      #pragma unroll
      for (int dy = 0; dy < 3; ++dy)
        #pragma unroll
        for (int dx = 0; dx < 3; ++dx)
          v += bands[jj + dy][(x + dx) * 50 + xs + dx];
      sc[x][xs] = v;
    }
    if (tid < 48) {
      float t = 0.0f;
      #pragma unroll
      for (int dy = 0; dy < 3; ++dy)
        #pragma unroll
        for (int dx = 0; dx < 3; ++dx) t += ssqb[jj + dy][tid + dx];
      rkl[tid] = 1.0f / sqrtf(t);
    }
    __syncthreads();
    if (tid < 192) {
      int r = tid >> 2, part = tid & 3;
      float best = -1e30f; int bxs = 0;
      #pragma unroll
      for (int i = 0; i < 12; ++i) {
        int xs = part * 12 + i;
        float v = sc[r][xs] * rkl[xs];
        if (v > best) { best = v; bxs = xs; }   // strict >: smallest xs within range
      }
      // quad combine (parts have increasing xs; ties keep smaller xs)
      #pragma unroll
      for (int o = 1; o < 4; o <<= 1) {
        float ov = __shfl_down(best, o);
        int oi = __shfl_down(bxs, o);
        if (ov > best || (ov == best && oi < bxs)) { best = ov; bxs = oi; }
      }
      if (part == 0) {
        int ps = ys * 48 + bxs;
        unsigned ub = __float_as_uint(best);
        unsigned enc = (ub & 0x80000000u) ? ~ub : (ub | 0x80000000u);
        u64 key = ((u64)enc << 32) | (u64)(2303 - ps);
        atomicMax(&rmax[(u64)b * HW + y * 48 + r], key);
      }
    }
    __syncthreads();
  }
}

// ---------------- reassemble: paste chosen patches + overlap normalize ----------------
__global__ void reassemble_kernel(const float* __restrict__ padS_cl, const u64* __restrict__ rmax,
                                  float* __restrict__ rF_cl) {
  int pix = blockIdx.x, b = blockIdx.y;
  int y = pix / 48, x = pix % 48;
  const u64* rm = rmax + (u64)b * HW;
  const float* S = padS_cl + (u64)b * (NPIX * NC);
  int ch = threadIdx.x;
  float sum = 0.0f;
  #pragma unroll
  for (int i = 0; i < 3; ++i)
    #pragma unroll
    for (int j = 0; j < 3; ++j) {
      int yn = y + 1 - i, xn = x + 1 - j;
      if (yn >= 0 && yn < 48 && xn >= 0 && xn < 48) {
        int ps = 2303 - (int)(unsigned)(rm[yn * 48 + xn] & 0xFFFFFFFFu);
        int ys = ps / 48, xs = ps % 48;
        sum += S[((ys + i) * 50 + xs + j) * NC + ch];
      }
    }
  float cy = (y == 0 || y == 47) ? 2.0f : 3.0f;
  float cx = (x == 0 || x == 47) ? 2.0f : 3.0f;
  rF_cl[(u64)b * (HW * NC) + pix * NC + ch] = sum / (cy * cx);
}

// ---------------- coloring: 64x64 tile, 4x4/thread, float4 LDS ----------------
__launch_bounds__(256)
__global__ void coloring_kernel(const float* __restrict__ Yf, const double* __restrict__ snorm,
                                const double* __restrict__ mean, const float* __restrict__ rF_cl,
                                float* __restrict__ out) {
  int b = blockIdx.z;
  const float* A = Yf + (2 + b) * MATSZ;
  const float* Bp = rF_cl + (u64)b * (HW * NC);
  const double* mn = mean + (2 + b) * NC;
  float cscale = (float)sqrt(snorm[2 + b]);
  int m0 = blockIdx.y * 64, n0 = blockIdx.x * 64;
  __shared__ float As[16][68], Bs[16][68];
  int tid = threadIdx.x;
  int tx = tid & 15, ty = tid >> 4;
  int li = tid >> 2, lk4 = tid & 3;
  int pix = tid >> 2, kq = (tid & 3) * 4;
  float acc[4][4] = {};
  for (int kc = 0; kc < 256; kc += 16) {
    __syncthreads();
    float4 va = *(const float4*)&A[(u64)(m0 + li) * NC + kc + lk4 * 4];
    As[lk4 * 4 + 0][li] = va.x; As[lk4 * 4 + 1][li] = va.y;
    As[lk4 * 4 + 2][li] = va.z; As[lk4 * 4 + 3][li] = va.w;
    float4 vb = *(const float4*)&Bp[(u64)(n0 + pix) * NC + kc + kq];
    Bs[kq + 0][pix] = vb.x; Bs[kq + 1][pix] = vb.y;
    Bs[kq + 2][pix] = vb.z; Bs[kq + 3][pix] = vb.w;
    __syncthreads();
    #pragma unroll
    for (int kk = 0; kk < 16; ++kk) {
      float4 a = *(const float4*)&As[kk][ty * 4];
      float4 b2 = *(const float4*)&Bs[kk][tx * 4];
      float av[4] = {a.x, a.y, a.z, a.w};
      float bv[4] = {b2.x, b2.y, b2.z, b2.w};
      #pragma unroll
      for (int i = 0; i < 4; ++i)
        #pragma unroll
        for (int j = 0; j < 4; ++j) acc[i][j] += av[i] * bv[j];
    }
  }
  #pragma unroll
  for (int i = 0; i < 4; ++i) {
    int row = m0 + ty * 4 + i;
    float madd = (float)mn[row];
    float4 v = make_float4(acc[i][0] * cscale + madd, acc[i][1] * cscale + madd,
                           acc[i][2] * cscale + madd, acc[i][3] * cscale + madd);
    *(float4*)&out[(u64)b * (NC * HW) + (u64)row * HW + n0 + tx * 4] = v;
  }
}

// ---------------- host ----------------
extern "C" void kernel_launch(void* const* d_in, const int* in_sizes, int n_in,
                              void* d_out, int out_size, void* d_ws, size_t ws_size,
                              hipStream_t stream) {
  const float* c = (const float*)d_in[0];
  const float* s = (const float*)d_in[1];
  float* out = (float*)d_out;

  char* ws = (char*)d_ws;
  size_t off = 0;
  auto alloc = [&](size_t bytes) {
    void* p = ws + off;
    off = (off + bytes + 255) & ~(size_t)255;
    return p;
  };
  double* mean   = (double*)alloc(4 * NC * sizeof(double));
  float* covp    = (float*)alloc((size_t)4 * NSLAB * MATSZ * sizeof(float));
  float* Ya      = (float*)alloc((size_t)4 * MATSZ * sizeof(float));
  float* Yb      = (float*)alloc((size_t)4 * MATSZ * sizeof(float));
  float* Za      = (float*)alloc((size_t)4 * MATSZ * sizeof(float));
  float* Zb      = (float*)alloc((size_t)4 * MATSZ * sizeof(float));
  float* T       = (float*)alloc((size_t)4 * MATSZ * sizeof(float));
  float* padC_cf = (float*)alloc((size_t)2 * NC * NPIXP * sizeof(float));
  float* padS_cf = (float*)alloc((size_t)2 * NC * NPIXP * sizeof(float));
  float* padS_cl = (float*)alloc((size_t)2 * NPIX * NC * sizeof(float));
  ushortt* padCk_hi = (ushortt*)alloc((size_t)2 * PMSZ * sizeof(ushortt));
  ushortt* padCk_lo = (ushortt*)alloc((size_t)2 * PMSZ * sizeof(ushortt));
  ushortt* padSk_hi = (ushortt*)alloc((size_t)2 * PMSZ * sizeof(ushortt));
  ushortt* padSk_lo = (ushortt*)alloc((size_t)2 * PMSZ * sizeof(ushortt));
  float* ssq     = (float*)alloc((size_t)2 * NPIX * sizeof(float));
  float* rF_cl   = (float*)alloc((size_t)2 * HW * NC * sizeof(float));
  float* G       = (float*)alloc((size_t)2 * GSZ * sizeof(float));
  u64*   rmax    = (u64*)alloc((size_t)2 * HW * sizeof(u64));
  double* snorm  = (double*)alloc(4 * sizeof(double));

  size_t padBytes = (size_t)(2 * NC * NPIXP + 2 * NC * NPIXP + 2 * NPIX * NC) * sizeof(float);
  hipMemsetAsync(padC_cf, 0, padBytes, stream);
  hipMemsetAsync(rmax, 0, (size_t)2 * HW * sizeof(u64) + 4 * sizeof(double), stream);

  mean_kernel<<<dim3(256, 4), 64, 0, stream>>>(c, s, mean, snorm);
  cov_part<<<dim3(4, 4, 4 * NSLAB), dim3(16, 16), 0, stream>>>(c, s, covp);
  cov_reduce<<<dim3(256, 4), 256, 0, stream>>>(covp, mean, snorm, Ya, Za);
  ns_gemm_Y<<<dim3(8, 8, 4), dim3(16, 16), 0, stream>>>(Ya, Za, Yb);  // Y1 = Y0*T0

  float *Yc = Yb, *Zc = Za, *Yn = Ya, *Zn = Zb;
  for (int it = 1; it < NS_ITERS; ++it) {
    ns_gemm_T<<<dim3(8, 8, 4), dim3(16, 16), 0, stream>>>(Zc, Yc, T);
    ns_gemm_YZ<<<dim3(8, 8, 8), dim3(16, 16), 0, stream>>>(Yc, Zc, T, Yn, Zn);
    float* t1 = Yc; Yc = Yn; Yn = t1;
    float* t2 = Zc; Zc = Zn; Zn = t2;
  }

  whiten_kernel<<<dim3(36, 4, 4), 256, 0, stream>>>(c, s, Zc, snorm, mean,
                                                    padC_cf, padS_cf, padS_cl);
  tsplit_kernel<<<dim3(40, 4), 256, 0, stream>>>(padC_cf, padS_cf,
                                                 padCk_hi, padCk_lo, padSk_hi, padSk_lo, ssq);

  gram_mfma<<<dim3(20, 40, 2), 256, 0, stream>>>(padCk_hi, padCk_lo, padSk_hi, padSk_lo, G);
  scoremax_kernel<<<dim3(12, 95, 2), 256, 0, stream>>>(G, ssq, rmax);

  reassemble_kernel<<<dim3(2304, 2), 256, 0, stream>>>(padS_cl, rmax, rF_cl);
  coloring_kernel<<<dim3(36, 4, 2), 256, 0, stream>>>(Yc, snorm, mean, rF_cl, out);
}

// Round 14
// 316.745 us; speedup vs baseline: 1.0555x; 1.0555x over previous
//
#include <hip/hip_runtime.h>
#include <math.h>

#define HW 2304       // 48*48
#define NC 256        // channels
#define NPIX 2500     // 50*50 padded grid
#define NPIXP 2560    // padded row stride for channel-first buffers / Gram
#define MATSZ 65536   // 256*256
#define NS_ITERS 5    // iter0 folded + 4 GEMM iterations
#define NSLAB 6
#define KSLAB 384     // 2304/6
#define PMSZ (2560 * 256)  // pixel-major buffer elems per batch
#define GSZ ((u64)NPIXP * NPIXP)

typedef unsigned long long u64;
typedef unsigned short ushortt;
typedef __attribute__((ext_vector_type(8))) short bhalf8;
typedef __attribute__((ext_vector_type(4))) float f32x4;

// ---------------- means + trace (f64): snorm[m] = 1.25*trace/256 ----------------
__global__ void mean_kernel(const float* __restrict__ c, const float* __restrict__ s,
                            double* __restrict__ mean, double* __restrict__ snorm) {
  int ch = blockIdx.x, m = blockIdx.y;
  const float* src = (m < 2 ? c + m * (NC * HW) : s + (m - 2) * (NC * HW)) + ch * HW;
  double acc = 0.0, acc2 = 0.0;
  for (int n = threadIdx.x; n < HW; n += 64) {
    double v = (double)src[n];
    acc += v; acc2 += v * v;
  }
  for (int o = 32; o > 0; o >>= 1) {
    acc += __shfl_down(acc, o);
    acc2 += __shfl_down(acc2, o);
  }
  if (threadIdx.x == 0) {
    mean[m * NC + ch] = acc / (double)HW;
    double diag = acc2 - acc * acc / (double)HW;   // = sum x^2 - HW*mu^2
    atomicAdd(&snorm[m], 1.25 * diag / 256.0);
  }
}

// ---------------- covariance partials: raw sum(x*y), 64x64 tile, 4x4/thread ----------------
__launch_bounds__(256)
__global__ void cov_part(const float* __restrict__ c, const float* __restrict__ s,
                         float* __restrict__ covp) {
  int z = blockIdx.z;
  int m = z / NSLAB, slab = z % NSLAB;
  const float* src = (m < 2 ? c + m * (NC * HW) : s + (m - 2) * (NC * HW));
  int i0 = blockIdx.y * 64, j0 = blockIdx.x * 64;
  int kb = slab * KSLAB;
  __shared__ float As[16][64], Bs[16][64];
  int tx = threadIdx.x, ty = threadIdx.y;
  int tid = ty * 16 + tx;
  int li = tid >> 2;
  int lk4 = tid & 3;
  float acc[4][4] = {};
  for (int kc = 0; kc < KSLAB; kc += 16) {
    __syncthreads();
    float4 va = *(const float4*)&src[(u64)(i0 + li) * HW + kb + kc + lk4 * 4];
    float4 vb = *(const float4*)&src[(u64)(j0 + li) * HW + kb + kc + lk4 * 4];
    As[lk4 * 4 + 0][li] = va.x; As[lk4 * 4 + 1][li] = va.y;
    As[lk4 * 4 + 2][li] = va.z; As[lk4 * 4 + 3][li] = va.w;
    Bs[lk4 * 4 + 0][li] = vb.x; Bs[lk4 * 4 + 1][li] = vb.y;
    Bs[lk4 * 4 + 2][li] = vb.z; Bs[lk4 * 4 + 3][li] = vb.w;
    __syncthreads();
    #pragma unroll
    for (int kk = 0; kk < 16; ++kk) {
      float4 a = *(const float4*)&As[kk][ty * 4];
      float4 b = *(const float4*)&Bs[kk][tx * 4];
      float av[4] = {a.x, a.y, a.z, a.w};
      float bv[4] = {b.x, b.y, b.z, b.w};
      #pragma unroll
      for (int i = 0; i < 4; ++i)
        #pragma unroll
        for (int j = 0; j < 4; ++j) acc[i][j] += av[i] * bv[j];
    }
  }
  float* Cp = covp + (u64)z * MATSZ;
  #pragma unroll
  for (int i = 0; i < 4; ++i) {
    float4 v = make_float4(acc[i][0], acc[i][1], acc[i][2], acc[i][3]);
    *(float4*)&Cp[(i0 + ty * 4 + i) * NC + j0 + tx * 4] = v;
  }
}

// grid(256,4), block 256. Y0 = (cov)/s; Z1 = T0 = 1.5I - 0.5*Y0 (NS iter0 folded).
__global__ void cov_reduce(const float* __restrict__ covp, const double* __restrict__ mean,
                           const double* __restrict__ snorm,
                           float* __restrict__ Y0, float* __restrict__ Z1) {
  int m = blockIdx.y;
  int row = blockIdx.x, col = threadIdx.x;
  int e = row * 256 + col;
  float v = 0.0f;
  #pragma unroll
  for (int slab = 0; slab < NSLAB; ++slab)
    v += covp[(u64)(m * NSLAB + slab) * MATSZ + e];
  double mi = mean[m * NC + row], mj = mean[m * NC + col];
  float res = (float)((double)v - (double)HW * mi * mj);
  float inv = (float)(1.0 / snorm[m]);
  float y0 = res * inv;
  Y0[m * MATSZ + e] = y0;
  Z1[m * MATSZ + e] = ((row == col) ? 1.5f : 0.0f) - 0.5f * y0;
}

// ---------------- Newton-Schulz GEMMs (256x256x256, f32) ----------------
__launch_bounds__(256)
__global__ void ns_gemm_Y(const float* __restrict__ Y0, const float* __restrict__ T0,
                          float* __restrict__ Y1) {
  int m = blockIdx.z;
  const float* A = Y0 + m * MATSZ;
  const float* B = T0 + m * MATSZ;
  float* Cp = Y1 + m * MATSZ;
  int m0 = blockIdx.y * 32, n0 = blockIdx.x * 32;
  __shared__ float As[32][33], Bs[32][33];
  int tx = threadIdx.x, ty = threadIdx.y;
  int tid = ty * 16 + tx;
  float acc[2][2] = {};
  for (int k0 = 0; k0 < 256; k0 += 32) {
    __syncthreads();
    #pragma unroll
    for (int l = 0; l < 4; ++l) {
      int idx = tid + l * 256;
      int r = idx >> 5, cc = idx & 31;
      As[r][cc] = A[(m0 + r) * NC + k0 + cc];
      Bs[r][cc] = B[(k0 + r) * NC + n0 + cc];
    }
    __syncthreads();
    #pragma unroll
    for (int kk = 0; kk < 32; ++kk) {
      float a0 = As[ty][kk], a1 = As[ty + 16][kk];
      float b0 = Bs[kk][tx], b1 = Bs[kk][tx + 16];
      acc[0][0] += a0 * b0; acc[0][1] += a0 * b1;
      acc[1][0] += a1 * b0; acc[1][1] += a1 * b1;
    }
  }
  #pragma unroll
  for (int i = 0; i < 2; ++i)
    #pragma unroll
    for (int j = 0; j < 2; ++j)
      Cp[(m0 + ty + 16 * i) * NC + n0 + tx + 16 * j] = acc[i][j];
}

__launch_bounds__(256)
__global__ void ns_gemm_T(const float* __restrict__ Zc, const float* __restrict__ Yc,
                          float* __restrict__ T) {
  int m = blockIdx.z;
  const float* A = Zc + m * MATSZ;
  const float* B = Yc + m * MATSZ;
  int m0 = blockIdx.y * 32, n0 = blockIdx.x * 32;
  __shared__ float As[32][33], Bs[32][33];
  int tx = threadIdx.x, ty = threadIdx.y;
  int tid = ty * 16 + tx;
  float acc[2][2] = {};
  for (int k0 = 0; k0 < 256; k0 += 32) {
    __syncthreads();
    #pragma unroll
    for (int l = 0; l < 4; ++l) {
      int idx = tid + l * 256;
      int r = idx >> 5, cc = idx & 31;
      As[r][cc] = A[(m0 + r) * NC + k0 + cc];
      Bs[r][cc] = B[(k0 + r) * NC + n0 + cc];
    }
    __syncthreads();
    #pragma unroll
    for (int kk = 0; kk < 32; ++kk) {
      float a0 = As[ty][kk], a1 = As[ty + 16][kk];
      float b0 = Bs[kk][tx], b1 = Bs[kk][tx + 16];
      acc[0][0] += a0 * b0; acc[0][1] += a0 * b1;
      acc[1][0] += a1 * b0; acc[1][1] += a1 * b1;
    }
  }
  float* Cp = T + m * MATSZ;
  #pragma unroll
  for (int i = 0; i < 2; ++i)
    #pragma unroll
    for (int j = 0; j < 2; ++j) {
      int row = m0 + ty + 16 * i, col = n0 + tx + 16 * j;
      Cp[row * NC + col] = (row == col ? 1.5f : 0.0f) - 0.5f * acc[i][j];
    }
}

__launch_bounds__(256)
__global__ void ns_gemm_YZ(const float* __restrict__ Yc, const float* __restrict__ Zc,
                           const float* __restrict__ T,
                           float* __restrict__ Yn, float* __restrict__ Zn) {
  int z = blockIdx.z;
  int m = z & 3;
  bool isY = (z < 4);
  const float* A = isY ? (Yc + m * MATSZ) : (T + m * MATSZ);
  const float* B = isY ? (T + m * MATSZ) : (Zc + m * MATSZ);
  float* Cp = isY ? (Yn + m * MATSZ) : (Zn + m * MATSZ);
  int m0 = blockIdx.y * 32, n0 = blockIdx.x * 32;
  __shared__ float As[32][33], Bs[32][33];
  int tx = threadIdx.x, ty = threadIdx.y;
  int tid = ty * 16 + tx;
  float acc[2][2] = {};
  for (int k0 = 0; k0 < 256; k0 += 32) {
    __syncthreads();
    #pragma unroll
    for (int l = 0; l < 4; ++l) {
      int idx = tid + l * 256;
      int r = idx >> 5, cc = idx & 31;
      As[r][cc] = A[(m0 + r) * NC + k0 + cc];
      Bs[r][cc] = B[(k0 + r) * NC + n0 + cc];
    }
    __syncthreads();
    #pragma unroll
    for (int kk = 0; kk < 32; ++kk) {
      float a0 = As[ty][kk], a1 = As[ty + 16][kk];
      float b0 = Bs[kk][tx], b1 = Bs[kk][tx + 16];
      acc[0][0] += a0 * b0; acc[0][1] += a0 * b1;
      acc[1][0] += a1 * b0; acc[1][1] += a1 * b1;
    }
  }
  #pragma unroll
  for (int i = 0; i < 2; ++i)
    #pragma unroll
    for (int j = 0; j < 2; ++j)
      Cp[(m0 + ty + 16 * i) * NC + n0 + tx + 16 * j] = acc[i][j];
}

// ---------------- whitening apply: 64x64 tile, 4x4/thread, float4 LDS ----------------
__launch_bounds__(256)
__global__ void whiten_kernel(const float* __restrict__ c, const float* __restrict__ s,
                              const float* __restrict__ Zf,
                              const double* __restrict__ snorm, const double* __restrict__ mean,
                              float* __restrict__ padC_cf, float* __restrict__ padS_cf,
                              float* __restrict__ padS_cl) {
  int mat = blockIdx.z;
  const float* src = (mat < 2 ? c + mat * (NC * HW) : s + (mat - 2) * (NC * HW));
  const float* A = Zf + mat * MATSZ;
  const double* mn = mean + mat * NC;
  float wscale = (float)(1.0 / sqrt(snorm[mat]));
  int m0 = blockIdx.y * 64, n0 = blockIdx.x * 64;
  __shared__ float As[16][68], Bs[16][68];
  int tid = threadIdx.x;
  int tx = tid & 15, ty = tid >> 4;
  int li = tid >> 2, lk4 = tid & 3;
  int kr = tid >> 4, p4 = (tid & 15) * 4;
  float acc[4][4] = {};
  for (int kc = 0; kc < 256; kc += 16) {
    __syncthreads();
    float4 va = *(const float4*)&A[(u64)(m0 + li) * NC + kc + lk4 * 4];
    As[lk4 * 4 + 0][li] = va.x; As[lk4 * 4 + 1][li] = va.y;
    As[lk4 * 4 + 2][li] = va.z; As[lk4 * 4 + 3][li] = va.w;
    float mk = (float)mn[kc + kr];
    float4 vb = *(const float4*)&src[(u64)(kc + kr) * HW + n0 + p4];
    vb.x -= mk; vb.y -= mk; vb.z -= mk; vb.w -= mk;
    *(float4*)&Bs[kr][p4] = vb;
    __syncthreads();
    #pragma unroll
    for (int kk = 0; kk < 16; ++kk) {
      float4 a = *(const float4*)&As[kk][ty * 4];
      float4 b = *(const float4*)&Bs[kk][tx * 4];
      float av[4] = {a.x, a.y, a.z, a.w};
      float bv[4] = {b.x, b.y, b.z, b.w};
      #pragma unroll
      for (int i = 0; i < 4; ++i)
        #pragma unroll
        for (int j = 0; j < 4; ++j) acc[i][j] += av[i] * bv[j];
    }
  }
  #pragma unroll
  for (int i = 0; i < 4; ++i) {
    int row = m0 + ty * 4 + i;
    #pragma unroll
    for (int j = 0; j < 4; ++j) {
      int n = n0 + tx * 4 + j;
      float v = acc[i][j] * wscale;
      int y = n / 48, x = n % 48;
      int ppos = (y + 1) * 50 + (x + 1);
      if (mat < 2) {
        padC_cf[(u64)mat * (NC * NPIXP) + row * NPIXP + ppos] = v;
      } else {
        padS_cf[(u64)(mat - 2) * (NC * NPIXP) + row * NPIXP + ppos] = v;
        padS_cl[(u64)(mat - 2) * (NPIX * NC) + ppos * NC + row] = v;
      }
    }
  }
}

// ---------------- transpose + bf16 split + per-pixel sumsq (style) ----------------
__launch_bounds__(256)
__global__ void tsplit_kernel(const float* __restrict__ padC_cf, const float* __restrict__ padS_cf,
                              ushortt* __restrict__ padCk_hi, ushortt* __restrict__ padCk_lo,
                              ushortt* __restrict__ padSk_hi, ushortt* __restrict__ padSk_lo,
                              float* __restrict__ ssq) {
  int p0 = blockIdx.x * 64;
  int by = blockIdx.y;
  const float* src = (by < 2) ? padC_cf + (u64)by * (NC * NPIXP)
                              : padS_cf + (u64)(by - 2) * (NC * NPIXP);
  ushortt* dhi = (by < 2) ? padCk_hi + (u64)by * PMSZ : padSk_hi + (u64)(by - 2) * PMSZ;
  ushortt* dlo = (by < 2) ? padCk_lo + (u64)by * PMSZ : padSk_lo + (u64)(by - 2) * PMSZ;
  __shared__ float Tk[64][68];
  int tid = threadIdx.x;
  int rr = tid >> 4, c4 = (tid & 15) * 4;
  int p = tid >> 2, kg = (tid & 3) * 16;
  float sq = 0.0f;
  for (int ks = 0; ks < 256; ks += 64) {
    __syncthreads();
    #pragma unroll
    for (int it = 0; it < 4; ++it) {
      int r = rr + it * 16;
      *(float4*)&Tk[r][c4] = *(const float4*)&src[(u64)(ks + r) * NPIXP + p0 + c4];
    }
    __syncthreads();
    __align__(16) ushortt h[16], lo[16];
    #pragma unroll
    for (int e = 0; e < 16; ++e) {
      float v = Tk[kg + e][p];
      sq += v * v;
      unsigned bb = __float_as_uint(v);
      unsigned hu = (bb + 0x7FFFu + ((bb >> 16) & 1u)) >> 16;
      float hf = __uint_as_float(hu << 16);
      float rres = v - hf;
      unsigned lb = __float_as_uint(rres);
      unsigned lu = (lb + 0x7FFFu + ((lb >> 16) & 1u)) >> 16;
      h[e] = (ushortt)hu;
      lo[e] = (ushortt)lu;
    }
    u64 off = (u64)(p0 + p) * 256 + ks + kg;
    *(uint4*)&dhi[off] = *(const uint4*)&h[0];
    *(uint4*)&dhi[off + 8] = *(const uint4*)&h[8];
    *(uint4*)&dlo[off] = *(const uint4*)&lo[0];
    *(uint4*)&dlo[off + 8] = *(const uint4*)&lo[8];
  }
  sq += __shfl_down(sq, 2);
  sq += __shfl_down(sq, 1);
  if (by >= 2 && (tid & 3) == 0 && (p0 + p) < NPIX)
    ssq[(u64)(by - 2) * NPIX + p0 + p] = sq;
}

// ---------------- MFMA Gram: G[p][q] = sum_k C[p][k]*S[q][k], split-bf16, z=batch -------
__launch_bounds__(256)
__global__ void gram_mfma(const ushortt* __restrict__ Ah_b, const ushortt* __restrict__ Al_b,
                          const ushortt* __restrict__ Bh_b, const ushortt* __restrict__ Bl_b,
                          float* __restrict__ Gb) {
  int bz = blockIdx.z;
  const ushortt* Ah_g = Ah_b + (u64)bz * PMSZ;
  const ushortt* Al_g = Al_b + (u64)bz * PMSZ;
  const ushortt* Bh_g = Bh_b + (u64)bz * PMSZ;
  const ushortt* Bl_g = Bl_b + (u64)bz * PMSZ;
  float* G = Gb + (u64)bz * GSZ;
  __shared__ ushortt As_hi[128 * 32], As_lo[128 * 32], Bs_hi[64 * 32], Bs_lo[64 * 32];
  int tid = threadIdx.x;
  int wv = tid >> 6, l = tid & 63, lr = l & 15, lk = l >> 4;
  int p0 = blockIdx.x * 128, q0 = blockIdx.y * 64;
  int arow = tid >> 2;
  int apart = (tid & 3) * 8;
  const ushortt* pAh0 = Ah_g + (u64)(p0 + arow) * 256 + apart;
  const ushortt* pAh1 = Ah_g + (u64)(p0 + arow + 64) * 256 + apart;
  const ushortt* pAl0 = Al_g + (u64)(p0 + arow) * 256 + apart;
  const ushortt* pAl1 = Al_g + (u64)(p0 + arow + 64) * 256 + apart;
  const ushortt* pBh  = Bh_g + (u64)(q0 + arow) * 256 + apart;
  const ushortt* pBl  = Bl_g + (u64)(q0 + arow) * 256 + apart;
  float4 rAh0 = *(const float4*)pAh0;
  float4 rAh1 = *(const float4*)pAh1;
  float4 rAl0 = *(const float4*)pAl0;
  float4 rAl1 = *(const float4*)pAl1;
  float4 rBh  = *(const float4*)pBh;
  float4 rBl  = *(const float4*)pBl;
  f32x4 acc[2][4];
  #pragma unroll
  for (int a = 0; a < 2; ++a)
    #pragma unroll
    for (int b = 0; b < 4; ++b)
      #pragma unroll
      for (int e = 0; e < 4; ++e) acc[a][b][e] = 0.0f;
  for (int k0 = 0; k0 < 256; k0 += 32) {
    __syncthreads();
    *(float4*)&As_hi[arow * 32 + apart] = rAh0;
    *(float4*)&As_hi[(arow + 64) * 32 + apart] = rAh1;
    *(float4*)&As_lo[arow * 32 + apart] = rAl0;
    *(float4*)&As_lo[(arow + 64) * 32 + apart] = rAl1;
    *(float4*)&Bs_hi[arow * 32 + apart] = rBh;
    *(float4*)&Bs_lo[arow * 32 + apart] = rBl;
    __syncthreads();
    if (k0 + 32 < 256) {
      rAh0 = *(const float4*)(pAh0 + k0 + 32);
      rAh1 = *(const float4*)(pAh1 + k0 + 32);
      rAl0 = *(const float4*)(pAl0 + k0 + 32);
      rAl1 = *(const float4*)(pAl1 + k0 + 32);
      rBh  = *(const float4*)(pBh + k0 + 32);
      rBl  = *(const float4*)(pBl + k0 + 32);
    }
    bhalf8 Ah[2], Al[2], Bh[4], Bl[4];
    #pragma unroll
    for (int a = 0; a < 2; ++a) {
      int off = (wv * 32 + a * 16 + lr) * 32 + lk * 8;
      Ah[a] = *(const bhalf8*)&As_hi[off];
      Al[a] = *(const bhalf8*)&As_lo[off];
    }
    #pragma unroll
    for (int b = 0; b < 4; ++b) {
      int off = (b * 16 + lr) * 32 + lk * 8;
      Bh[b] = *(const bhalf8*)&Bs_hi[off];
      Bl[b] = *(const bhalf8*)&Bs_lo[off];
    }
    #pragma unroll
    for (int a = 0; a < 2; ++a)
      #pragma unroll
      for (int b = 0; b < 4; ++b) {
        acc[a][b] = __builtin_amdgcn_mfma_f32_16x16x32_bf16(Ah[a], Bh[b], acc[a][b], 0, 0, 0);
        acc[a][b] = __builtin_amdgcn_mfma_f32_16x16x32_bf16(Ah[a], Bl[b], acc[a][b], 0, 0, 0);
        acc[a][b] = __builtin_amdgcn_mfma_f32_16x16x32_bf16(Al[a], Bh[b], acc[a][b], 0, 0, 0);
      }
  }
  #pragma unroll
  for (int a = 0; a < 2; ++a)
    #pragma unroll
    for (int b = 0; b < 4; ++b)
      #pragma unroll
      for (int r = 0; r < 4; ++r) {
        int p = p0 + wv * 32 + a * 16 + lk * 4 + r;
        int q = q0 + b * 16 + lr;
        G[(u64)p * NPIXP + q] = acc[a][b][r];
      }
}

// ---------------- scoremax: per-(y,ys) block, one dy-band at a time (low LDS) ----------
// grid(48, 48, 2), block 256. LDS ~21KB -> high occupancy. Bit-identical sums to R12.
__launch_bounds__(256)
__global__ void scoremax_kernel(const float* __restrict__ Gb, const float* __restrict__ ssq,
                                u64* __restrict__ rmax) {
  int y = blockIdx.x, ys = blockIdx.y, b = blockIdx.z;
  const float* G = Gb + (u64)b * GSZ;
  const float* sq = ssq + (u64)b * NPIX;
  __shared__ float Gt1[50][52];
  __shared__ float sc[48][52];
  __shared__ float sr[152];
  __shared__ float rkl[48];
  int tid = threadIdx.x;
  for (int dy = 0; dy < 3; ++dy) {
    if (dy > 0) __syncthreads();           // prior stencil done before Gt1 overwrite
    for (int t = tid; t < 2500; t += 256) {
      int u = t / 50, v = t - u * 50;
      Gt1[u][v] = G[(u64)((y + dy) * 50 + u) * NPIXP + (ys + dy) * 50 + v];
    }
    if (dy == 0 && tid < 150) {
      int d = tid / 50, v = tid - d * 50;
      sr[d * 50 + v] = sq[(ys + d) * 50 + v];
    }
    __syncthreads();
    if (dy == 0 && tid < 48) {
      float t = 0.0f;
      #pragma unroll
      for (int d = 0; d < 3; ++d)
        #pragma unroll
        for (int dx = 0; dx < 3; ++dx) t += sr[d * 50 + tid + dx];
      rkl[tid] = 1.0f / sqrtf(t);
    }
    #pragma unroll
    for (int k = 0; k < 9; ++k) {
      int idx = tid + k * 256;
      int x = idx / 48, xs = idx - x * 48;
      float v = Gt1[x][xs] + Gt1[x + 1][xs + 1] + Gt1[x + 2][xs + 2];
      sc[x][xs] = (dy == 0) ? v : sc[x][xs] + v;   // same (x,xs)->thread map each dy: no race
    }
  }
  __syncthreads();
  if (tid < 192) {
    int r = tid >> 2, part = tid & 3;
    float best = -1e30f; int bxs = 0;
    #pragma unroll
    for (int i = 0; i < 12; ++i) {
      int xs = part * 12 + i;
      float v = sc[r][xs] * rkl[xs];
      if (v > best) { best = v; bxs = xs; }   // strict >: smallest xs within range
    }
    #pragma unroll
    for (int o = 1; o < 4; o <<= 1) {        // parts have increasing xs; ties keep smaller
      float ov = __shfl_down(best, o);
      int oi = __shfl_down(bxs, o);
      if (ov > best || (ov == best && oi < bxs)) { best = ov; bxs = oi; }
    }
    if (part == 0) {
      int ps = ys * 48 + bxs;
      unsigned ub = __float_as_uint(best);
      unsigned enc = (ub & 0x80000000u) ? ~ub : (ub | 0x80000000u);
      u64 key = ((u64)enc << 32) | (u64)(2303 - ps);
      atomicMax(&rmax[(u64)b * HW + y * 48 + r], key);
    }
  }
}

// ---------------- reassemble: paste chosen patches + overlap normalize ----------------
__global__ void reassemble_kernel(const float* __restrict__ padS_cl, const u64* __restrict__ rmax,
                                  float* __restrict__ rF_cl) {
  int pix = blockIdx.x, b = blockIdx.y;
  int y = pix / 48, x = pix % 48;
  const u64* rm = rmax + (u64)b * HW;
  const float* S = padS_cl + (u64)b * (NPIX * NC);
  int ch = threadIdx.x;
  float sum = 0.0f;
  #pragma unroll
  for (int i = 0; i < 3; ++i)
    #pragma unroll
    for (int j = 0; j < 3; ++j) {
      int yn = y + 1 - i, xn = x + 1 - j;
      if (yn >= 0 && yn < 48 && xn >= 0 && xn < 48) {
        int ps = 2303 - (int)(unsigned)(rm[yn * 48 + xn] & 0xFFFFFFFFu);
        int ys = ps / 48, xs = ps % 48;
        sum += S[((ys + i) * 50 + xs + j) * NC + ch];
      }
    }
  float cy = (y == 0 || y == 47) ? 2.0f : 3.0f;
  float cx = (x == 0 || x == 47) ? 2.0f : 3.0f;
  rF_cl[(u64)b * (HW * NC) + pix * NC + ch] = sum / (cy * cx);
}

// ---------------- coloring: 64x64 tile, 4x4/thread, float4 LDS ----------------
__launch_bounds__(256)
__global__ void coloring_kernel(const float* __restrict__ Yf, const double* __restrict__ snorm,
                                const double* __restrict__ mean, const float* __restrict__ rF_cl,
                                float* __restrict__ out) {
  int b = blockIdx.z;
  const float* A = Yf + (2 + b) * MATSZ;
  const float* Bp = rF_cl + (u64)b * (HW * NC);
  const double* mn = mean + (2 + b) * NC;
  float cscale = (float)sqrt(snorm[2 + b]);
  int m0 = blockIdx.y * 64, n0 = blockIdx.x * 64;
  __shared__ float As[16][68], Bs[16][68];
  int tid = threadIdx.x;
  int tx = tid & 15, ty = tid >> 4;
  int li = tid >> 2, lk4 = tid & 3;
  int pix = tid >> 2, kq = (tid & 3) * 4;
  float acc[4][4] = {};
  for (int kc = 0; kc < 256; kc += 16) {
    __syncthreads();
    float4 va = *(const float4*)&A[(u64)(m0 + li) * NC + kc + lk4 * 4];
    As[lk4 * 4 + 0][li] = va.x; As[lk4 * 4 + 1][li] = va.y;
    As[lk4 * 4 + 2][li] = va.z; As[lk4 * 4 + 3][li] = va.w;
    float4 vb = *(const float4*)&Bp[(u64)(n0 + pix) * NC + kc + kq];
    Bs[kq + 0][pix] = vb.x; Bs[kq + 1][pix] = vb.y;
    Bs[kq + 2][pix] = vb.z; Bs[kq + 3][pix] = vb.w;
    __syncthreads();
    #pragma unroll
    for (int kk = 0; kk < 16; ++kk) {
      float4 a = *(const float4*)&As[kk][ty * 4];
      float4 b2 = *(const float4*)&Bs[kk][tx * 4];
      float av[4] = {a.x, a.y, a.z, a.w};
      float bv[4] = {b2.x, b2.y, b2.z, b2.w};
      #pragma unroll
      for (int i = 0; i < 4; ++i)
        #pragma unroll
        for (int j = 0; j < 4; ++j) acc[i][j] += av[i] * bv[j];
    }
  }
  #pragma unroll
  for (int i = 0; i < 4; ++i) {
    int row = m0 + ty * 4 + i;
    float madd = (float)mn[row];
    float4 v = make_float4(acc[i][0] * cscale + madd, acc[i][1] * cscale + madd,
                           acc[i][2] * cscale + madd, acc[i][3] * cscale + madd);
    *(float4*)&out[(u64)b * (NC * HW) + (u64)row * HW + n0 + tx * 4] = v;
  }
}

// ---------------- host ----------------
extern "C" void kernel_launch(void* const* d_in, const int* in_sizes, int n_in,
                              void* d_out, int out_size, void* d_ws, size_t ws_size,
                              hipStream_t stream) {
  const float* c = (const float*)d_in[0];
  const float* s = (const float*)d_in[1];
  float* out = (float*)d_out;

  char* ws = (char*)d_ws;
  size_t off = 0;
  auto alloc = [&](size_t bytes) {
    void* p = ws + off;
    off = (off + bytes + 255) & ~(size_t)255;
    return p;
  };
  double* mean   = (double*)alloc(4 * NC * sizeof(double));
  float* covp    = (float*)alloc((size_t)4 * NSLAB * MATSZ * sizeof(float));
  float* Ya      = (float*)alloc((size_t)4 * MATSZ * sizeof(float));
  float* Yb      = (float*)alloc((size_t)4 * MATSZ * sizeof(float));
  float* Za      = (float*)alloc((size_t)4 * MATSZ * sizeof(float));
  float* Zb      = (float*)alloc((size_t)4 * MATSZ * sizeof(float));
  float* T       = (float*)alloc((size_t)4 * MATSZ * sizeof(float));
  float* padC_cf = (float*)alloc((size_t)2 * NC * NPIXP * sizeof(float));
  float* padS_cf = (float*)alloc((size_t)2 * NC * NPIXP * sizeof(float));
  float* padS_cl = (float*)alloc((size_t)2 * NPIX * NC * sizeof(float));
  ushortt* padCk_hi = (ushortt*)alloc((size_t)2 * PMSZ * sizeof(ushortt));
  ushortt* padCk_lo = (ushortt*)alloc((size_t)2 * PMSZ * sizeof(ushortt));
  ushortt* padSk_hi = (ushortt*)alloc((size_t)2 * PMSZ * sizeof(ushortt));
  ushortt* padSk_lo = (ushortt*)alloc((size_t)2 * PMSZ * sizeof(ushortt));
  float* ssq     = (float*)alloc((size_t)2 * NPIX * sizeof(float));
  float* rF_cl   = (float*)alloc((size_t)2 * HW * NC * sizeof(float));
  float* G       = (float*)alloc((size_t)2 * GSZ * sizeof(float));
  u64*   rmax    = (u64*)alloc((size_t)2 * HW * sizeof(u64));
  double* snorm  = (double*)alloc(4 * sizeof(double));

  size_t padBytes = (size_t)(2 * NC * NPIXP + 2 * NC * NPIXP + 2 * NPIX * NC) * sizeof(float);
  hipMemsetAsync(padC_cf, 0, padBytes, stream);
  hipMemsetAsync(rmax, 0, (size_t)2 * HW * sizeof(u64) + 4 * sizeof(double), stream);

  mean_kernel<<<dim3(256, 4), 64, 0, stream>>>(c, s, mean, snorm);
  cov_part<<<dim3(4, 4, 4 * NSLAB), dim3(16, 16), 0, stream>>>(c, s, covp);
  cov_reduce<<<dim3(256, 4), 256, 0, stream>>>(covp, mean, snorm, Ya, Za);
  ns_gemm_Y<<<dim3(8, 8, 4), dim3(16, 16), 0, stream>>>(Ya, Za, Yb);  // Y1 = Y0*T0

  float *Yc = Yb, *Zc = Za, *Yn = Ya, *Zn = Zb;
  for (int it = 1; it < NS_ITERS; ++it) {
    ns_gemm_T<<<dim3(8, 8, 4), dim3(16, 16), 0, stream>>>(Zc, Yc, T);
    ns_gemm_YZ<<<dim3(8, 8, 8), dim3(16, 16), 0, stream>>>(Yc, Zc, T, Yn, Zn);
    float* t1 = Yc; Yc = Yn; Yn = t1;
    float* t2 = Zc; Zc = Zn; Zn = t2;
  }

  whiten_kernel<<<dim3(36, 4, 4), 256, 0, stream>>>(c, s, Zc, snorm, mean,
                                                    padC_cf, padS_cf, padS_cl);
  tsplit_kernel<<<dim3(40, 4), 256, 0, stream>>>(padC_cf, padS_cf,
                                                 padCk_hi, padCk_lo, padSk_hi, padSk_lo, ssq);

  gram_mfma<<<dim3(20, 40, 2), 256, 0, stream>>>(padCk_hi, padCk_lo, padSk_hi, padSk_lo, G);
  scoremax_kernel<<<dim3(48, 48, 2), 256, 0, stream>>>(G, ssq, rmax);

  reassemble_kernel<<<dim3(2304, 2), 256, 0, stream>>>(padS_cl, rmax, rF_cl);
  coloring_kernel<<<dim3(36, 4, 2), 256, 0, stream>>>(Yc, snorm, mean, rF_cl, out);
}

// Round 15
// 308.254 us; speedup vs baseline: 1.0846x; 1.0275x over previous
//
#include <hip/hip_runtime.h>
#include <math.h>

#define HW 2304       // 48*48
#define NC 256        // channels
#define NPIX 2500     // 50*50 padded grid
#define NPIXP 2560    // padded row stride for channel-first buffers / Gram
#define MATSZ 65536   // 256*256
#define NS_ITERS 5    // iter0 folded + 4 GEMM iterations
#define NSLAB 6
#define KSLAB 384     // 2304/6
#define PMSZ (2560 * 256)  // pixel-major buffer elems per batch
#define GSZ ((u64)NPIXP * NPIXP)

typedef unsigned long long u64;
typedef unsigned short ushortt;
typedef __attribute__((ext_vector_type(8))) short bhalf8;
typedef __attribute__((ext_vector_type(4))) float f32x4;

// ---------------- means + trace (f64): snorm[m] = 1.25*trace/256 ----------------
__global__ void mean_kernel(const float* __restrict__ c, const float* __restrict__ s,
                            double* __restrict__ mean, double* __restrict__ snorm) {
  int ch = blockIdx.x, m = blockIdx.y;
  const float* src = (m < 2 ? c + m * (NC * HW) : s + (m - 2) * (NC * HW)) + ch * HW;
  double acc = 0.0, acc2 = 0.0;
  for (int n = threadIdx.x; n < HW; n += 64) {
    double v = (double)src[n];
    acc += v; acc2 += v * v;
  }
  for (int o = 32; o > 0; o >>= 1) {
    acc += __shfl_down(acc, o);
    acc2 += __shfl_down(acc2, o);
  }
  if (threadIdx.x == 0) {
    mean[m * NC + ch] = acc / (double)HW;
    double diag = acc2 - acc * acc / (double)HW;   // = sum x^2 - HW*mu^2
    atomicAdd(&snorm[m], 1.25 * diag / 256.0);
  }
}

// ---------------- covariance partials: raw sum(x*y), 64x64 tile, 4x4/thread ----------------
__launch_bounds__(256)
__global__ void cov_part(const float* __restrict__ c, const float* __restrict__ s,
                         float* __restrict__ covp) {
  int z = blockIdx.z;
  int m = z / NSLAB, slab = z % NSLAB;
  const float* src = (m < 2 ? c + m * (NC * HW) : s + (m - 2) * (NC * HW));
  int i0 = blockIdx.y * 64, j0 = blockIdx.x * 64;
  int kb = slab * KSLAB;
  __shared__ float As[16][64], Bs[16][64];
  int tx = threadIdx.x, ty = threadIdx.y;
  int tid = ty * 16 + tx;
  int li = tid >> 2;
  int lk4 = tid & 3;
  float acc[4][4] = {};
  for (int kc = 0; kc < KSLAB; kc += 16) {
    __syncthreads();
    float4 va = *(const float4*)&src[(u64)(i0 + li) * HW + kb + kc + lk4 * 4];
    float4 vb = *(const float4*)&src[(u64)(j0 + li) * HW + kb + kc + lk4 * 4];
    As[lk4 * 4 + 0][li] = va.x; As[lk4 * 4 + 1][li] = va.y;
    As[lk4 * 4 + 2][li] = va.z; As[lk4 * 4 + 3][li] = va.w;
    Bs[lk4 * 4 + 0][li] = vb.x; Bs[lk4 * 4 + 1][li] = vb.y;
    Bs[lk4 * 4 + 2][li] = vb.z; Bs[lk4 * 4 + 3][li] = vb.w;
    __syncthreads();
    #pragma unroll
    for (int kk = 0; kk < 16; ++kk) {
      float4 a = *(const float4*)&As[kk][ty * 4];
      float4 b = *(const float4*)&Bs[kk][tx * 4];
      float av[4] = {a.x, a.y, a.z, a.w};
      float bv[4] = {b.x, b.y, b.z, b.w};
      #pragma unroll
      for (int i = 0; i < 4; ++i)
        #pragma unroll
        for (int j = 0; j < 4; ++j) acc[i][j] += av[i] * bv[j];
    }
  }
  float* Cp = covp + (u64)z * MATSZ;
  #pragma unroll
  for (int i = 0; i < 4; ++i) {
    float4 v = make_float4(acc[i][0], acc[i][1], acc[i][2], acc[i][3]);
    *(float4*)&Cp[(i0 + ty * 4 + i) * NC + j0 + tx * 4] = v;
  }
}

// grid(256,4), block 256. Y0 = (cov)/s; Z1 = T0 = 1.5I - 0.5*Y0 (NS iter0 folded).
__global__ void cov_reduce(const float* __restrict__ covp, const double* __restrict__ mean,
                           const double* __restrict__ snorm,
                           float* __restrict__ Y0, float* __restrict__ Z1) {
  int m = blockIdx.y;
  int row = blockIdx.x, col = threadIdx.x;
  int e = row * 256 + col;
  float v = 0.0f;
  #pragma unroll
  for (int slab = 0; slab < NSLAB; ++slab)
    v += covp[(u64)(m * NSLAB + slab) * MATSZ + e];
  double mi = mean[m * NC + row], mj = mean[m * NC + col];
  float res = (float)((double)v - (double)HW * mi * mj);
  float inv = (float)(1.0 / snorm[m]);
  float y0 = res * inv;
  Y0[m * MATSZ + e] = y0;
  Z1[m * MATSZ + e] = ((row == col) ? 1.5f : 0.0f) - 0.5f * y0;
}

// ---------------- Newton-Schulz GEMMs (256x256x256, f32) ----------------
__launch_bounds__(256)
__global__ void ns_gemm_Y(const float* __restrict__ Y0, const float* __restrict__ T0,
                          float* __restrict__ Y1) {
  int m = blockIdx.z;
  const float* A = Y0 + m * MATSZ;
  const float* B = T0 + m * MATSZ;
  float* Cp = Y1 + m * MATSZ;
  int m0 = blockIdx.y * 32, n0 = blockIdx.x * 32;
  __shared__ float As[32][33], Bs[32][33];
  int tx = threadIdx.x, ty = threadIdx.y;
  int tid = ty * 16 + tx;
  float acc[2][2] = {};
  for (int k0 = 0; k0 < 256; k0 += 32) {
    __syncthreads();
    #pragma unroll
    for (int l = 0; l < 4; ++l) {
      int idx = tid + l * 256;
      int r = idx >> 5, cc = idx & 31;
      As[r][cc] = A[(m0 + r) * NC + k0 + cc];
      Bs[r][cc] = B[(k0 + r) * NC + n0 + cc];
    }
    __syncthreads();
    #pragma unroll
    for (int kk = 0; kk < 32; ++kk) {
      float a0 = As[ty][kk], a1 = As[ty + 16][kk];
      float b0 = Bs[kk][tx], b1 = Bs[kk][tx + 16];
      acc[0][0] += a0 * b0; acc[0][1] += a0 * b1;
      acc[1][0] += a1 * b0; acc[1][1] += a1 * b1;
    }
  }
  #pragma unroll
  for (int i = 0; i < 2; ++i)
    #pragma unroll
    for (int j = 0; j < 2; ++j)
      Cp[(m0 + ty + 16 * i) * NC + n0 + tx + 16 * j] = acc[i][j];
}

__launch_bounds__(256)
__global__ void ns_gemm_T(const float* __restrict__ Zc, const float* __restrict__ Yc,
                          float* __restrict__ T) {
  int m = blockIdx.z;
  const float* A = Zc + m * MATSZ;
  const float* B = Yc + m * MATSZ;
  int m0 = blockIdx.y * 32, n0 = blockIdx.x * 32;
  __shared__ float As[32][33], Bs[32][33];
  int tx = threadIdx.x, ty = threadIdx.y;
  int tid = ty * 16 + tx;
  float acc[2][2] = {};
  for (int k0 = 0; k0 < 256; k0 += 32) {
    __syncthreads();
    #pragma unroll
    for (int l = 0; l < 4; ++l) {
      int idx = tid + l * 256;
      int r = idx >> 5, cc = idx & 31;
      As[r][cc] = A[(m0 + r) * NC + k0 + cc];
      Bs[r][cc] = B[(k0 + r) * NC + n0 + cc];
    }
    __syncthreads();
    #pragma unroll
    for (int kk = 0; kk < 32; ++kk) {
      float a0 = As[ty][kk], a1 = As[ty + 16][kk];
      float b0 = Bs[kk][tx], b1 = Bs[kk][tx + 16];
      acc[0][0] += a0 * b0; acc[0][1] += a0 * b1;
      acc[1][0] += a1 * b0; acc[1][1] += a1 * b1;
    }
  }
  float* Cp = T + m * MATSZ;
  #pragma unroll
  for (int i = 0; i < 2; ++i)
    #pragma unroll
    for (int j = 0; j < 2; ++j) {
      int row = m0 + ty + 16 * i, col = n0 + tx + 16 * j;
      Cp[row * NC + col] = (row == col ? 1.5f : 0.0f) - 0.5f * acc[i][j];
    }
}

__launch_bounds__(256)
__global__ void ns_gemm_YZ(const float* __restrict__ Yc, const float* __restrict__ Zc,
                           const float* __restrict__ T,
                           float* __restrict__ Yn, float* __restrict__ Zn) {
  int z = blockIdx.z;
  int m = z & 3;
  bool isY = (z < 4);
  const float* A = isY ? (Yc + m * MATSZ) : (T + m * MATSZ);
  const float* B = isY ? (T + m * MATSZ) : (Zc + m * MATSZ);
  float* Cp = isY ? (Yn + m * MATSZ) : (Zn + m * MATSZ);
  int m0 = blockIdx.y * 32, n0 = blockIdx.x * 32;
  __shared__ float As[32][33], Bs[32][33];
  int tx = threadIdx.x, ty = threadIdx.y;
  int tid = ty * 16 + tx;
  float acc[2][2] = {};
  for (int k0 = 0; k0 < 256; k0 += 32) {
    __syncthreads();
    #pragma unroll
    for (int l = 0; l < 4; ++l) {
      int idx = tid + l * 256;
      int r = idx >> 5, cc = idx & 31;
      As[r][cc] = A[(m0 + r) * NC + k0 + cc];
      Bs[r][cc] = B[(k0 + r) * NC + n0 + cc];
    }
    __syncthreads();
    #pragma unroll
    for (int kk = 0; kk < 32; ++kk) {
      float a0 = As[ty][kk], a1 = As[ty + 16][kk];
      float b0 = Bs[kk][tx], b1 = Bs[kk][tx + 16];
      acc[0][0] += a0 * b0; acc[0][1] += a0 * b1;
      acc[1][0] += a1 * b0; acc[1][1] += a1 * b1;
    }
  }
  #pragma unroll
  for (int i = 0; i < 2; ++i)
    #pragma unroll
    for (int j = 0; j < 2; ++j)
      Cp[(m0 + ty + 16 * i) * NC + n0 + tx + 16 * j] = acc[i][j];
}

// ---------------- whitening apply: 64x64 tile, 4x4/thread, float4 LDS ----------------
__launch_bounds__(256)
__global__ void whiten_kernel(const float* __restrict__ c, const float* __restrict__ s,
                              const float* __restrict__ Zf,
                              const double* __restrict__ snorm, const double* __restrict__ mean,
                              float* __restrict__ padC_cf, float* __restrict__ padS_cf,
                              float* __restrict__ padS_cl) {
  int mat = blockIdx.z;
  const float* src = (mat < 2 ? c + mat * (NC * HW) : s + (mat - 2) * (NC * HW));
  const float* A = Zf + mat * MATSZ;
  const double* mn = mean + mat * NC;
  float wscale = (float)(1.0 / sqrt(snorm[mat]));
  int m0 = blockIdx.y * 64, n0 = blockIdx.x * 64;
  __shared__ float As[16][68], Bs[16][68];
  int tid = threadIdx.x;
  int tx = tid & 15, ty = tid >> 4;
  int li = tid >> 2, lk4 = tid & 3;
  int kr = tid >> 4, p4 = (tid & 15) * 4;
  float acc[4][4] = {};
  for (int kc = 0; kc < 256; kc += 16) {
    __syncthreads();
    float4 va = *(const float4*)&A[(u64)(m0 + li) * NC + kc + lk4 * 4];
    As[lk4 * 4 + 0][li] = va.x; As[lk4 * 4 + 1][li] = va.y;
    As[lk4 * 4 + 2][li] = va.z; As[lk4 * 4 + 3][li] = va.w;
    float mk = (float)mn[kc + kr];
    float4 vb = *(const float4*)&src[(u64)(kc + kr) * HW + n0 + p4];
    vb.x -= mk; vb.y -= mk; vb.z -= mk; vb.w -= mk;
    *(float4*)&Bs[kr][p4] = vb;
    __syncthreads();
    #pragma unroll
    for (int kk = 0; kk < 16; ++kk) {
      float4 a = *(const float4*)&As[kk][ty * 4];
      float4 b = *(const float4*)&Bs[kk][tx * 4];
      float av[4] = {a.x, a.y, a.z, a.w};
      float bv[4] = {b.x, b.y, b.z, b.w};
      #pragma unroll
      for (int i = 0; i < 4; ++i)
        #pragma unroll
        for (int j = 0; j < 4; ++j) acc[i][j] += av[i] * bv[j];
    }
  }
  #pragma unroll
  for (int i = 0; i < 4; ++i) {
    int row = m0 + ty * 4 + i;
    #pragma unroll
    for (int j = 0; j < 4; ++j) {
      int n = n0 + tx * 4 + j;
      float v = acc[i][j] * wscale;
      int y = n / 48, x = n % 48;
      int ppos = (y + 1) * 50 + (x + 1);
      if (mat < 2) {
        padC_cf[(u64)mat * (NC * NPIXP) + row * NPIXP + ppos] = v;
      } else {
        padS_cf[(u64)(mat - 2) * (NC * NPIXP) + row * NPIXP + ppos] = v;
        padS_cl[(u64)(mat - 2) * (NPIX * NC) + ppos * NC + row] = v;
      }
    }
  }
}

// ---------------- transpose + bf16 split + per-pixel sumsq (style) ----------------
__launch_bounds__(256)
__global__ void tsplit_kernel(const float* __restrict__ padC_cf, const float* __restrict__ padS_cf,
                              ushortt* __restrict__ padCk_hi, ushortt* __restrict__ padCk_lo,
                              ushortt* __restrict__ padSk_hi, ushortt* __restrict__ padSk_lo,
                              float* __restrict__ ssq) {
  int p0 = blockIdx.x * 64;
  int by = blockIdx.y;
  const float* src = (by < 2) ? padC_cf + (u64)by * (NC * NPIXP)
                              : padS_cf + (u64)(by - 2) * (NC * NPIXP);
  ushortt* dhi = (by < 2) ? padCk_hi + (u64)by * PMSZ : padSk_hi + (u64)(by - 2) * PMSZ;
  ushortt* dlo = (by < 2) ? padCk_lo + (u64)by * PMSZ : padSk_lo + (u64)(by - 2) * PMSZ;
  __shared__ float Tk[64][68];
  int tid = threadIdx.x;
  int rr = tid >> 4, c4 = (tid & 15) * 4;
  int p = tid >> 2, kg = (tid & 3) * 16;
  float sq = 0.0f;
  for (int ks = 0; ks < 256; ks += 64) {
    __syncthreads();
    #pragma unroll
    for (int it = 0; it < 4; ++it) {
      int r = rr + it * 16;
      *(float4*)&Tk[r][c4] = *(const float4*)&src[(u64)(ks + r) * NPIXP + p0 + c4];
    }
    __syncthreads();
    __align__(16) ushortt h[16], lo[16];
    #pragma unroll
    for (int e = 0; e < 16; ++e) {
      float v = Tk[kg + e][p];
      sq += v * v;
      unsigned bb = __float_as_uint(v);
      unsigned hu = (bb + 0x7FFFu + ((bb >> 16) & 1u)) >> 16;
      float hf = __uint_as_float(hu << 16);
      float rres = v - hf;
      unsigned lb = __float_as_uint(rres);
      unsigned lu = (lb + 0x7FFFu + ((lb >> 16) & 1u)) >> 16;
      h[e] = (ushortt)hu;
      lo[e] = (ushortt)lu;
    }
    u64 off = (u64)(p0 + p) * 256 + ks + kg;
    *(uint4*)&dhi[off] = *(const uint4*)&h[0];
    *(uint4*)&dhi[off + 8] = *(const uint4*)&h[8];
    *(uint4*)&dlo[off] = *(const uint4*)&lo[0];
    *(uint4*)&dlo[off + 8] = *(const uint4*)&lo[8];
  }
  sq += __shfl_down(sq, 2);
  sq += __shfl_down(sq, 1);
  if (by >= 2 && (tid & 3) == 0 && (p0 + p) < NPIX)
    ssq[(u64)(by - 2) * NPIX + p0 + p] = sq;
}

// ---------------- MFMA Gram: G[p][q] = sum_k C[p][k]*S[q][k], split-bf16, z=batch -------
__launch_bounds__(256)
__global__ void gram_mfma(const ushortt* __restrict__ Ah_b, const ushortt* __restrict__ Al_b,
                          const ushortt* __restrict__ Bh_b, const ushortt* __restrict__ Bl_b,
                          float* __restrict__ Gb) {
  int bz = blockIdx.z;
  const ushortt* Ah_g = Ah_b + (u64)bz * PMSZ;
  const ushortt* Al_g = Al_b + (u64)bz * PMSZ;
  const ushortt* Bh_g = Bh_b + (u64)bz * PMSZ;
  const ushortt* Bl_g = Bl_b + (u64)bz * PMSZ;
  float* G = Gb + (u64)bz * GSZ;
  __shared__ ushortt As_hi[128 * 32], As_lo[128 * 32], Bs_hi[64 * 32], Bs_lo[64 * 32];
  int tid = threadIdx.x;
  int wv = tid >> 6, l = tid & 63, lr = l & 15, lk = l >> 4;
  int p0 = blockIdx.x * 128, q0 = blockIdx.y * 64;
  int arow = tid >> 2;
  int apart = (tid & 3) * 8;
  const ushortt* pAh0 = Ah_g + (u64)(p0 + arow) * 256 + apart;
  const ushortt* pAh1 = Ah_g + (u64)(p0 + arow + 64) * 256 + apart;
  const ushortt* pAl0 = Al_g + (u64)(p0 + arow) * 256 + apart;
  const ushortt* pAl1 = Al_g + (u64)(p0 + arow + 64) * 256 + apart;
  const ushortt* pBh  = Bh_g + (u64)(q0 + arow) * 256 + apart;
  const ushortt* pBl  = Bl_g + (u64)(q0 + arow) * 256 + apart;
  float4 rAh0 = *(const float4*)pAh0;
  float4 rAh1 = *(const float4*)pAh1;
  float4 rAl0 = *(const float4*)pAl0;
  float4 rAl1 = *(const float4*)pAl1;
  float4 rBh  = *(const float4*)pBh;
  float4 rBl  = *(const float4*)pBl;
  f32x4 acc[2][4];
  #pragma unroll
  for (int a = 0; a < 2; ++a)
    #pragma unroll
    for (int b = 0; b < 4; ++b)
      #pragma unroll
      for (int e = 0; e < 4; ++e) acc[a][b][e] = 0.0f;
  for (int k0 = 0; k0 < 256; k0 += 32) {
    __syncthreads();
    *(float4*)&As_hi[arow * 32 + apart] = rAh0;
    *(float4*)&As_hi[(arow + 64) * 32 + apart] = rAh1;
    *(float4*)&As_lo[arow * 32 + apart] = rAl0;
    *(float4*)&As_lo[(arow + 64) * 32 + apart] = rAl1;
    *(float4*)&Bs_hi[arow * 32 + apart] = rBh;
    *(float4*)&Bs_lo[arow * 32 + apart] = rBl;
    __syncthreads();
    if (k0 + 32 < 256) {
      rAh0 = *(const float4*)(pAh0 + k0 + 32);
      rAh1 = *(const float4*)(pAh1 + k0 + 32);
      rAl0 = *(const float4*)(pAl0 + k0 + 32);
      rAl1 = *(const float4*)(pAl1 + k0 + 32);
      rBh  = *(const float4*)(pBh + k0 + 32);
      rBl  = *(const float4*)(pBl + k0 + 32);
    }
    bhalf8 Ah[2], Al[2], Bh[4], Bl[4];
    #pragma unroll
    for (int a = 0; a < 2; ++a) {
      int off = (wv * 32 + a * 16 + lr) * 32 + lk * 8;
      Ah[a] = *(const bhalf8*)&As_hi[off];
      Al[a] = *(const bhalf8*)&As_lo[off];
    }
    #pragma unroll
    for (int b = 0; b < 4; ++b) {
      int off = (b * 16 + lr) * 32 + lk * 8;
      Bh[b] = *(const bhalf8*)&Bs_hi[off];
      Bl[b] = *(const bhalf8*)&Bs_lo[off];
    }
    #pragma unroll
    for (int a = 0; a < 2; ++a)
      #pragma unroll
      for (int b = 0; b < 4; ++b) {
        acc[a][b] = __builtin_amdgcn_mfma_f32_16x16x32_bf16(Ah[a], Bh[b], acc[a][b], 0, 0, 0);
        acc[a][b] = __builtin_amdgcn_mfma_f32_16x16x32_bf16(Ah[a], Bl[b], acc[a][b], 0, 0, 0);
        acc[a][b] = __builtin_amdgcn_mfma_f32_16x16x32_bf16(Al[a], Bh[b], acc[a][b], 0, 0, 0);
      }
  }
  #pragma unroll
  for (int a = 0; a < 2; ++a)
    #pragma unroll
    for (int b = 0; b < 4; ++b)
      #pragma unroll
      for (int r = 0; r < 4; ++r) {
        int p = p0 + wv * 32 + a * 16 + lk * 4 + r;
        int q = q0 + b * 16 + lr;
        G[(u64)p * NPIXP + q] = acc[a][b][r];
      }
}

// ---------------- scoremax: per-(y,ys) block, register stencil acc, float2 loads --------
// grid(48, 48, 2), block 256. Bit-identical summation order to R14.
__launch_bounds__(256)
__global__ void scoremax_kernel(const float* __restrict__ Gb, const float* __restrict__ ssq,
                                u64* __restrict__ rmax) {
  int y = blockIdx.x, ys = blockIdx.y, b = blockIdx.z;
  const float* G = Gb + (u64)b * GSZ;
  const float* sq = ssq + (u64)b * NPIX;
  __shared__ float Gt1[50][52];
  __shared__ float sc[48][52];
  __shared__ float sr[152];
  __shared__ float rkl[48];
  int tid = threadIdx.x;
  float racc[9];
  for (int dy = 0; dy < 3; ++dy) {
    if (dy > 0) __syncthreads();           // prior stencil done before Gt1 overwrite
    // band load: 1250 float2 (row starts always even -> aligned)
    for (int t = tid; t < 1250; t += 256) {
      int u = t / 25, v2 = (t - u * 25) * 2;
      float2 g = *(const float2*)&G[(u64)((y + dy) * 50 + u) * NPIXP + (ys + dy) * 50 + v2];
      *(float2*)&Gt1[u][v2] = g;
    }
    if (dy == 0 && tid < 150) {
      int d = tid / 50, v = tid - d * 50;
      sr[d * 50 + v] = sq[(ys + d) * 50 + v];
    }
    __syncthreads();
    if (dy == 0 && tid < 48) {
      float t = 0.0f;
      #pragma unroll
      for (int d = 0; d < 3; ++d)
        #pragma unroll
        for (int dx = 0; dx < 3; ++dx) t += sr[d * 50 + tid + dx];
      rkl[tid] = 1.0f / sqrtf(t);
    }
    #pragma unroll
    for (int k = 0; k < 9; ++k) {
      int idx = tid + k * 256;
      int x = idx / 48, xs = idx - x * 48;
      float v = Gt1[x][xs] + Gt1[x + 1][xs + 1] + Gt1[x + 2][xs + 2];
      racc[k] = (dy == 0) ? v : racc[k] + v;
    }
  }
  #pragma unroll
  for (int k = 0; k < 9; ++k) {
    int idx = tid + k * 256;
    int x = idx / 48, xs = idx - x * 48;
    sc[x][xs] = racc[k];
  }
  __syncthreads();
  if (tid < 192) {
    int r = tid >> 2, part = tid & 3;
    float best = -1e30f; int bxs = 0;
    #pragma unroll
    for (int i = 0; i < 12; ++i) {
      int xs = part * 12 + i;
      float v = sc[r][xs] * rkl[xs];
      if (v > best) { best = v; bxs = xs; }   // strict >: smallest xs within range
    }
    #pragma unroll
    for (int o = 1; o < 4; o <<= 1) {        // parts have increasing xs; ties keep smaller
      float ov = __shfl_down(best, o);
      int oi = __shfl_down(bxs, o);
      if (ov > best || (ov == best && oi < bxs)) { best = ov; bxs = oi; }
    }
    if (part == 0) {
      int ps = ys * 48 + bxs;
      unsigned ub = __float_as_uint(best);
      unsigned enc = (ub & 0x80000000u) ? ~ub : (ub | 0x80000000u);
      u64 key = ((u64)enc << 32) | (u64)(2303 - ps);
      atomicMax(&rmax[(u64)b * HW + y * 48 + r], key);
    }
  }
}

// ---------------- reassemble: paste chosen patches + overlap normalize ----------------
__global__ void reassemble_kernel(const float* __restrict__ padS_cl, const u64* __restrict__ rmax,
                                  float* __restrict__ rF_cl) {
  int pix = blockIdx.x, b = blockIdx.y;
  int y = pix / 48, x = pix % 48;
  const u64* rm = rmax + (u64)b * HW;
  const float* S = padS_cl + (u64)b * (NPIX * NC);
  int ch = threadIdx.x;
  float sum = 0.0f;
  #pragma unroll
  for (int i = 0; i < 3; ++i)
    #pragma unroll
    for (int j = 0; j < 3; ++j) {
      int yn = y + 1 - i, xn = x + 1 - j;
      if (yn >= 0 && yn < 48 && xn >= 0 && xn < 48) {
        int ps = 2303 - (int)(unsigned)(rm[yn * 48 + xn] & 0xFFFFFFFFu);
        int ys = ps / 48, xs = ps % 48;
        sum += S[((ys + i) * 50 + xs + j) * NC + ch];
      }
    }
  float cy = (y == 0 || y == 47) ? 2.0f : 3.0f;
  float cx = (x == 0 || x == 47) ? 2.0f : 3.0f;
  rF_cl[(u64)b * (HW * NC) + pix * NC + ch] = sum / (cy * cx);
}

// ---------------- coloring: 64x64 tile, 4x4/thread, float4 LDS ----------------
__launch_bounds__(256)
__global__ void coloring_kernel(const float* __restrict__ Yf, const double* __restrict__ snorm,
                                const double* __restrict__ mean, const float* __restrict__ rF_cl,
                                float* __restrict__ out) {
  int b = blockIdx.z;
  const float* A = Yf + (2 + b) * MATSZ;
  const float* Bp = rF_cl + (u64)b * (HW * NC);
  const double* mn = mean + (2 + b) * NC;
  float cscale = (float)sqrt(snorm[2 + b]);
  int m0 = blockIdx.y * 64, n0 = blockIdx.x * 64;
  __shared__ float As[16][68], Bs[16][68];
  int tid = threadIdx.x;
  int tx = tid & 15, ty = tid >> 4;
  int li = tid >> 2, lk4 = tid & 3;
  int pix = tid >> 2, kq = (tid & 3) * 4;
  float acc[4][4] = {};
  for (int kc = 0; kc < 256; kc += 16) {
    __syncthreads();
    float4 va = *(const float4*)&A[(u64)(m0 + li) * NC + kc + lk4 * 4];
    As[lk4 * 4 + 0][li] = va.x; As[lk4 * 4 + 1][li] = va.y;
    As[lk4 * 4 + 2][li] = va.z; As[lk4 * 4 + 3][li] = va.w;
    float4 vb = *(const float4*)&Bp[(u64)(n0 + pix) * NC + kc + kq];
    Bs[kq + 0][pix] = vb.x; Bs[kq + 1][pix] = vb.y;
    Bs[kq + 2][pix] = vb.z; Bs[kq + 3][pix] = vb.w;
    __syncthreads();
    #pragma unroll
    for (int kk = 0; kk < 16; ++kk) {
      float4 a = *(const float4*)&As[kk][ty * 4];
      float4 b2 = *(const float4*)&Bs[kk][tx * 4];
      float av[4] = {a.x, a.y, a.z, a.w};
      float bv[4] = {b2.x, b2.y, b2.z, b2.w};
      #pragma unroll
      for (int i = 0; i < 4; ++i)
        #pragma unroll
        for (int j = 0; j < 4; ++j) acc[i][j] += av[i] * bv[j];
    }
  }
  #pragma unroll
  for (int i = 0; i < 4; ++i) {
    int row = m0 + ty * 4 + i;
    float madd = (float)mn[row];
    float4 v = make_float4(acc[i][0] * cscale + madd, acc[i][1] * cscale + madd,
                           acc[i][2] * cscale + madd, acc[i][3] * cscale + madd);
    *(float4*)&out[(u64)b * (NC * HW) + (u64)row * HW + n0 + tx * 4] = v;
  }
}

// ---------------- host ----------------
extern "C" void kernel_launch(void* const* d_in, const int* in_sizes, int n_in,
                              void* d_out, int out_size, void* d_ws, size_t ws_size,
                              hipStream_t stream) {
  const float* c = (const float*)d_in[0];
  const float* s = (const float*)d_in[1];
  float* out = (float*)d_out;

  char* ws = (char*)d_ws;
  size_t off = 0;
  auto alloc = [&](size_t bytes) {
    void* p = ws + off;
    off = (off + bytes + 255) & ~(size_t)255;
    return p;
  };
  double* mean   = (double*)alloc(4 * NC * sizeof(double));
  float* covp    = (float*)alloc((size_t)4 * NSLAB * MATSZ * sizeof(float));
  float* Ya      = (float*)alloc((size_t)4 * MATSZ * sizeof(float));
  float* Yb      = (float*)alloc((size_t)4 * MATSZ * sizeof(float));
  float* Za      = (float*)alloc((size_t)4 * MATSZ * sizeof(float));
  float* Zb      = (float*)alloc((size_t)4 * MATSZ * sizeof(float));
  float* T       = (float*)alloc((size_t)4 * MATSZ * sizeof(float));
  float* padC_cf = (float*)alloc((size_t)2 * NC * NPIXP * sizeof(float));
  float* padS_cf = (float*)alloc((size_t)2 * NC * NPIXP * sizeof(float));
  float* padS_cl = (float*)alloc((size_t)2 * NPIX * NC * sizeof(float));
  ushortt* padCk_hi = (ushortt*)alloc((size_t)2 * PMSZ * sizeof(ushortt));
  ushortt* padCk_lo = (ushortt*)alloc((size_t)2 * PMSZ * sizeof(ushortt));
  ushortt* padSk_hi = (ushortt*)alloc((size_t)2 * PMSZ * sizeof(ushortt));
  ushortt* padSk_lo = (ushortt*)alloc((size_t)2 * PMSZ * sizeof(ushortt));
  float* ssq     = (float*)alloc((size_t)2 * NPIX * sizeof(float));
  float* rF_cl   = (float*)alloc((size_t)2 * HW * NC * sizeof(float));
  float* G       = (float*)alloc((size_t)2 * GSZ * sizeof(float));
  u64*   rmax    = (u64*)alloc((size_t)2 * HW * sizeof(u64));
  double* snorm  = (double*)alloc(4 * sizeof(double));

  size_t padBytes = (size_t)(2 * NC * NPIXP + 2 * NC * NPIXP + 2 * NPIX * NC) * sizeof(float);
  hipMemsetAsync(padC_cf, 0, padBytes, stream);
  hipMemsetAsync(rmax, 0, (size_t)2 * HW * sizeof(u64) + 4 * sizeof(double), stream);

  mean_kernel<<<dim3(256, 4), 64, 0, stream>>>(c, s, mean, snorm);
  cov_part<<<dim3(4, 4, 4 * NSLAB), dim3(16, 16), 0, stream>>>(c, s, covp);
  cov_reduce<<<dim3(256, 4), 256, 0, stream>>>(covp, mean, snorm, Ya, Za);
  ns_gemm_Y<<<dim3(8, 8, 4), dim3(16, 16), 0, stream>>>(Ya, Za, Yb);  // Y1 = Y0*T0

  float *Yc = Yb, *Zc = Za, *Yn = Ya, *Zn = Zb;
  for (int it = 1; it < NS_ITERS; ++it) {
    ns_gemm_T<<<dim3(8, 8, 4), dim3(16, 16), 0, stream>>>(Zc, Yc, T);
    ns_gemm_YZ<<<dim3(8, 8, 8), dim3(16, 16), 0, stream>>>(Yc, Zc, T, Yn, Zn);
    float* t1 = Yc; Yc = Yn; Yn = t1;
    float* t2 = Zc; Zc = Zn; Zn = t2;
  }

  whiten_kernel<<<dim3(36, 4, 4), 256, 0, stream>>>(c, s, Zc, snorm, mean,
                                                    padC_cf, padS_cf, padS_cl);
  tsplit_kernel<<<dim3(40, 4), 256, 0, stream>>>(padC_cf, padS_cf,
                                                 padCk_hi, padCk_lo, padSk_hi, padSk_lo, ssq);

  gram_mfma<<<dim3(20, 40, 2), 256, 0, stream>>>(padCk_hi, padCk_lo, padSk_hi, padSk_lo, G);
  scoremax_kernel<<<dim3(48, 48, 2), 256, 0, stream>>>(G, ssq, rmax);

  reassemble_kernel<<<dim3(2304, 2), 256, 0, stream>>>(padS_cl, rmax, rF_cl);
  coloring_kernel<<<dim3(36, 4, 2), 256, 0, stream>>>(Yc, snorm, mean, rF_cl, out);
}

// Round 16
// 300.631 us; speedup vs baseline: 1.1121x; 1.0254x over previous
//
#include <hip/hip_runtime.h>
#include <math.h>

#define HW 2304       // 48*48
#define NC 256        // channels
#define NPIX 2500     // 50*50 padded grid
#define NPIXP 2560    // padded row stride for Gram
#define MATSZ 65536   // 256*256
#define NS_ITERS 5    // iter0 folded + 4 GEMM iterations
#define NSLAB 6
#define KSLAB 384     // 2304/6
#define PMSZ (2560 * 256)  // pixel-major buffer elems per batch
#define GSZ ((u64)NPIXP * NPIXP)

typedef unsigned long long u64;
typedef unsigned short ushortt;
typedef __attribute__((ext_vector_type(8))) short bhalf8;
typedef __attribute__((ext_vector_type(4))) float f32x4;

// ---------------- means + trace (f64): snorm[m] = 1.25*trace/256 ----------------
__global__ void mean_kernel(const float* __restrict__ c, const float* __restrict__ s,
                            double* __restrict__ mean, double* __restrict__ snorm) {
  int ch = blockIdx.x, m = blockIdx.y;
  const float* src = (m < 2 ? c + m * (NC * HW) : s + (m - 2) * (NC * HW)) + ch * HW;
  double acc = 0.0, acc2 = 0.0;
  for (int n = threadIdx.x; n < HW; n += 64) {
    double v = (double)src[n];
    acc += v; acc2 += v * v;
  }
  for (int o = 32; o > 0; o >>= 1) {
    acc += __shfl_down(acc, o);
    acc2 += __shfl_down(acc2, o);
  }
  if (threadIdx.x == 0) {
    mean[m * NC + ch] = acc / (double)HW;
    double diag = acc2 - acc * acc / (double)HW;   // = sum x^2 - HW*mu^2
    atomicAdd(&snorm[m], 1.25 * diag / 256.0);
  }
}

// ---------------- covariance partials: raw sum(x*y), 64x64 tile, 4x4/thread ----------------
__launch_bounds__(256)
__global__ void cov_part(const float* __restrict__ c, const float* __restrict__ s,
                         float* __restrict__ covp) {
  int z = blockIdx.z;
  int m = z / NSLAB, slab = z % NSLAB;
  const float* src = (m < 2 ? c + m * (NC * HW) : s + (m - 2) * (NC * HW));
  int i0 = blockIdx.y * 64, j0 = blockIdx.x * 64;
  int kb = slab * KSLAB;
  __shared__ float As[16][64], Bs[16][64];
  int tx = threadIdx.x, ty = threadIdx.y;
  int tid = ty * 16 + tx;
  int li = tid >> 2;
  int lk4 = tid & 3;
  float acc[4][4] = {};
  for (int kc = 0; kc < KSLAB; kc += 16) {
    __syncthreads();
    float4 va = *(const float4*)&src[(u64)(i0 + li) * HW + kb + kc + lk4 * 4];
    float4 vb = *(const float4*)&src[(u64)(j0 + li) * HW + kb + kc + lk4 * 4];
    As[lk4 * 4 + 0][li] = va.x; As[lk4 * 4 + 1][li] = va.y;
    As[lk4 * 4 + 2][li] = va.z; As[lk4 * 4 + 3][li] = va.w;
    Bs[lk4 * 4 + 0][li] = vb.x; Bs[lk4 * 4 + 1][li] = vb.y;
    Bs[lk4 * 4 + 2][li] = vb.z; Bs[lk4 * 4 + 3][li] = vb.w;
    __syncthreads();
    #pragma unroll
    for (int kk = 0; kk < 16; ++kk) {
      float4 a = *(const float4*)&As[kk][ty * 4];
      float4 b = *(const float4*)&Bs[kk][tx * 4];
      float av[4] = {a.x, a.y, a.z, a.w};
      float bv[4] = {b.x, b.y, b.z, b.w};
      #pragma unroll
      for (int i = 0; i < 4; ++i)
        #pragma unroll
        for (int j = 0; j < 4; ++j) acc[i][j] += av[i] * bv[j];
    }
  }
  float* Cp = covp + (u64)z * MATSZ;
  #pragma unroll
  for (int i = 0; i < 4; ++i) {
    float4 v = make_float4(acc[i][0], acc[i][1], acc[i][2], acc[i][3]);
    *(float4*)&Cp[(i0 + ty * 4 + i) * NC + j0 + tx * 4] = v;
  }
}

// grid(256,4), block 256. Y0 = (cov)/s; Z1 = T0 = 1.5I - 0.5*Y0 (NS iter0 folded).
__global__ void cov_reduce(const float* __restrict__ covp, const double* __restrict__ mean,
                           const double* __restrict__ snorm,
                           float* __restrict__ Y0, float* __restrict__ Z1) {
  int m = blockIdx.y;
  int row = blockIdx.x, col = threadIdx.x;
  int e = row * 256 + col;
  float v = 0.0f;
  #pragma unroll
  for (int slab = 0; slab < NSLAB; ++slab)
    v += covp[(u64)(m * NSLAB + slab) * MATSZ + e];
  double mi = mean[m * NC + row], mj = mean[m * NC + col];
  float res = (float)((double)v - (double)HW * mi * mj);
  float inv = (float)(1.0 / snorm[m]);
  float y0 = res * inv;
  Y0[m * MATSZ + e] = y0;
  Z1[m * MATSZ + e] = ((row == col) ? 1.5f : 0.0f) - 0.5f * y0;
}

// ---------------- Newton-Schulz GEMMs (256x256x256, f32) ----------------
__launch_bounds__(256)
__global__ void ns_gemm_Y(const float* __restrict__ Y0, const float* __restrict__ T0,
                          float* __restrict__ Y1) {
  int m = blockIdx.z;
  const float* A = Y0 + m * MATSZ;
  const float* B = T0 + m * MATSZ;
  float* Cp = Y1 + m * MATSZ;
  int m0 = blockIdx.y * 32, n0 = blockIdx.x * 32;
  __shared__ float As[32][33], Bs[32][33];
  int tx = threadIdx.x, ty = threadIdx.y;
  int tid = ty * 16 + tx;
  float acc[2][2] = {};
  for (int k0 = 0; k0 < 256; k0 += 32) {
    __syncthreads();
    #pragma unroll
    for (int l = 0; l < 4; ++l) {
      int idx = tid + l * 256;
      int r = idx >> 5, cc = idx & 31;
      As[r][cc] = A[(m0 + r) * NC + k0 + cc];
      Bs[r][cc] = B[(k0 + r) * NC + n0 + cc];
    }
    __syncthreads();
    #pragma unroll
    for (int kk = 0; kk < 32; ++kk) {
      float a0 = As[ty][kk], a1 = As[ty + 16][kk];
      float b0 = Bs[kk][tx], b1 = Bs[kk][tx + 16];
      acc[0][0] += a0 * b0; acc[0][1] += a0 * b1;
      acc[1][0] += a1 * b0; acc[1][1] += a1 * b1;
    }
  }
  #pragma unroll
  for (int i = 0; i < 2; ++i)
    #pragma unroll
    for (int j = 0; j < 2; ++j)
      Cp[(m0 + ty + 16 * i) * NC + n0 + tx + 16 * j] = acc[i][j];
}

__launch_bounds__(256)
__global__ void ns_gemm_T(const float* __restrict__ Zc, const float* __restrict__ Yc,
                          float* __restrict__ T) {
  int m = blockIdx.z;
  const float* A = Zc + m * MATSZ;
  const float* B = Yc + m * MATSZ;
  int m0 = blockIdx.y * 32, n0 = blockIdx.x * 32;
  __shared__ float As[32][33], Bs[32][33];
  int tx = threadIdx.x, ty = threadIdx.y;
  int tid = ty * 16 + tx;
  float acc[2][2] = {};
  for (int k0 = 0; k0 < 256; k0 += 32) {
    __syncthreads();
    #pragma unroll
    for (int l = 0; l < 4; ++l) {
      int idx = tid + l * 256;
      int r = idx >> 5, cc = idx & 31;
      As[r][cc] = A[(m0 + r) * NC + k0 + cc];
      Bs[r][cc] = B[(k0 + r) * NC + n0 + cc];
    }
    __syncthreads();
    #pragma unroll
    for (int kk = 0; kk < 32; ++kk) {
      float a0 = As[ty][kk], a1 = As[ty + 16][kk];
      float b0 = Bs[kk][tx], b1 = Bs[kk][tx + 16];
      acc[0][0] += a0 * b0; acc[0][1] += a0 * b1;
      acc[1][0] += a1 * b0; acc[1][1] += a1 * b1;
    }
  }
  float* Cp = T + m * MATSZ;
  #pragma unroll
  for (int i = 0; i < 2; ++i)
    #pragma unroll
    for (int j = 0; j < 2; ++j) {
      int row = m0 + ty + 16 * i, col = n0 + tx + 16 * j;
      Cp[row * NC + col] = (row == col ? 1.5f : 0.0f) - 0.5f * acc[i][j];
    }
}

__launch_bounds__(256)
__global__ void ns_gemm_YZ(const float* __restrict__ Yc, const float* __restrict__ Zc,
                           const float* __restrict__ T,
                           float* __restrict__ Yn, float* __restrict__ Zn) {
  int z = blockIdx.z;
  int m = z & 3;
  bool isY = (z < 4);
  const float* A = isY ? (Yc + m * MATSZ) : (T + m * MATSZ);
  const float* B = isY ? (T + m * MATSZ) : (Zc + m * MATSZ);
  float* Cp = isY ? (Yn + m * MATSZ) : (Zn + m * MATSZ);
  int m0 = blockIdx.y * 32, n0 = blockIdx.x * 32;
  __shared__ float As[32][33], Bs[32][33];
  int tx = threadIdx.x, ty = threadIdx.y;
  int tid = ty * 16 + tx;
  float acc[2][2] = {};
  for (int k0 = 0; k0 < 256; k0 += 32) {
    __syncthreads();
    #pragma unroll
    for (int l = 0; l < 4; ++l) {
      int idx = tid + l * 256;
      int r = idx >> 5, cc = idx & 31;
      As[r][cc] = A[(m0 + r) * NC + k0 + cc];
      Bs[r][cc] = B[(k0 + r) * NC + n0 + cc];
    }
    __syncthreads();
    #pragma unroll
    for (int kk = 0; kk < 32; ++kk) {
      float a0 = As[ty][kk], a1 = As[ty + 16][kk];
      float b0 = Bs[kk][tx], b1 = Bs[kk][tx + 16];
      acc[0][0] += a0 * b0; acc[0][1] += a0 * b1;
      acc[1][0] += a1 * b0; acc[1][1] += a1 * b1;
    }
  }
  #pragma unroll
  for (int i = 0; i < 2; ++i)
    #pragma unroll
    for (int j = 0; j < 2; ++j)
      Cp[(m0 + ty + 16 * i) * NC + n0 + tx + 16 * j] = acc[i][j];
}

// ---------------- whitening apply + fused bf16 split (pixel-major) + ssq partials --------
// grid(36, 4, 4), block 256. 64ch x 64pix tile. norm = (1/sqrt(s)) * Zf * (x - mean).
__launch_bounds__(256)
__global__ void whiten_kernel(const float* __restrict__ c, const float* __restrict__ s,
                              const float* __restrict__ Zf,
                              const double* __restrict__ snorm, const double* __restrict__ mean,
                              ushortt* __restrict__ padCk_hi, ushortt* __restrict__ padCk_lo,
                              ushortt* __restrict__ padSk_hi, ushortt* __restrict__ padSk_lo,
                              float* __restrict__ padS_cl, float* __restrict__ ssqp) {
  int mat = blockIdx.z;
  const float* src = (mat < 2 ? c + mat * (NC * HW) : s + (mat - 2) * (NC * HW));
  const float* A = Zf + mat * MATSZ;
  const double* mn = mean + mat * NC;
  float wscale = (float)(1.0 / sqrt(snorm[mat]));
  int m0 = blockIdx.y * 64, n0 = blockIdx.x * 64;
  __shared__ float As[16][68], Bs[16][68];
  __shared__ float part[16][64];
  int tid = threadIdx.x;
  int tx = tid & 15, ty = tid >> 4;
  int li = tid >> 2, lk4 = tid & 3;
  int kr = tid >> 4, p4 = (tid & 15) * 4;
  float acc[4][4] = {};
  for (int kc = 0; kc < 256; kc += 16) {
    __syncthreads();
    float4 va = *(const float4*)&A[(u64)(m0 + li) * NC + kc + lk4 * 4];
    As[lk4 * 4 + 0][li] = va.x; As[lk4 * 4 + 1][li] = va.y;
    As[lk4 * 4 + 2][li] = va.z; As[lk4 * 4 + 3][li] = va.w;
    float mk = (float)mn[kc + kr];
    float4 vb = *(const float4*)&src[(u64)(kc + kr) * HW + n0 + p4];
    vb.x -= mk; vb.y -= mk; vb.z -= mk; vb.w -= mk;
    *(float4*)&Bs[kr][p4] = vb;
    __syncthreads();
    #pragma unroll
    for (int kk = 0; kk < 16; ++kk) {
      float4 a = *(const float4*)&As[kk][ty * 4];
      float4 b = *(const float4*)&Bs[kk][tx * 4];
      float av[4] = {a.x, a.y, a.z, a.w};
      float bv[4] = {b.x, b.y, b.z, b.w};
      #pragma unroll
      for (int i = 0; i < 4; ++i)
        #pragma unroll
        for (int j = 0; j < 4; ++j) acc[i][j] += av[i] * bv[j];
    }
  }
  bool isC = (mat < 2);
  ushortt* dhi = isC ? padCk_hi + (u64)mat * PMSZ : padSk_hi + (u64)(mat - 2) * PMSZ;
  ushortt* dlo = isC ? padCk_lo + (u64)mat * PMSZ : padSk_lo + (u64)(mat - 2) * PMSZ;
  float* scl = padS_cl + (u64)(mat < 2 ? 0 : mat - 2) * (NPIX * NC);
  #pragma unroll
  for (int j = 0; j < 4; ++j) {
    int n = n0 + tx * 4 + j;
    int yy = n / 48, xx = n % 48;
    int ppos = (yy + 1) * 50 + (xx + 1);
    __align__(8) ushortt h4[4], l4[4];
    float psq = 0.0f;
    #pragma unroll
    for (int i = 0; i < 4; ++i) {
      float v = acc[i][j] * wscale;
      psq += v * v;
      unsigned bb = __float_as_uint(v);
      unsigned hu = (bb + 0x7FFFu + ((bb >> 16) & 1u)) >> 16;
      float hf = __uint_as_float(hu << 16);
      float rres = v - hf;
      unsigned lb = __float_as_uint(rres);
      unsigned lu = (lb + 0x7FFFu + ((lb >> 16) & 1u)) >> 16;
      h4[i] = (ushortt)hu;
      l4[i] = (ushortt)lu;
      if (!isC) scl[(u64)ppos * NC + m0 + ty * 4 + i] = v;
    }
    u64 off = (u64)ppos * 256 + m0 + ty * 4;
    *(ushort4*)&dhi[off] = *(const ushort4*)h4;
    *(ushort4*)&dlo[off] = *(const ushort4*)l4;
    part[ty][tx * 4 + j] = psq;
  }
  __syncthreads();
  if (!isC && tid < 64) {
    float t = 0.0f;
    #pragma unroll
    for (int q = 0; q < 16; ++q) t += part[q][tid];    // fixed ty order: deterministic
    int n = n0 + tid;
    int yy = n / 48, xx = n % 48;
    int ppos = (yy + 1) * 50 + (xx + 1);
    ssqp[((u64)(mat - 2) * 4 + blockIdx.y) * NPIX + ppos] = t;
  }
}

// ---------------- MFMA Gram: G[p][q] = sum_k C[p][k]*S[q][k], split-bf16, z=batch -------
__launch_bounds__(256)
__global__ void gram_mfma(const ushortt* __restrict__ Ah_b, const ushortt* __restrict__ Al_b,
                          const ushortt* __restrict__ Bh_b, const ushortt* __restrict__ Bl_b,
                          float* __restrict__ Gb) {
  int bz = blockIdx.z;
  const ushortt* Ah_g = Ah_b + (u64)bz * PMSZ;
  const ushortt* Al_g = Al_b + (u64)bz * PMSZ;
  const ushortt* Bh_g = Bh_b + (u64)bz * PMSZ;
  const ushortt* Bl_g = Bl_b + (u64)bz * PMSZ;
  float* G = Gb + (u64)bz * GSZ;
  __shared__ ushortt As_hi[128 * 32], As_lo[128 * 32], Bs_hi[64 * 32], Bs_lo[64 * 32];
  int tid = threadIdx.x;
  int wv = tid >> 6, l = tid & 63, lr = l & 15, lk = l >> 4;
  int p0 = blockIdx.x * 128, q0 = blockIdx.y * 64;
  int arow = tid >> 2;
  int apart = (tid & 3) * 8;
  const ushortt* pAh0 = Ah_g + (u64)(p0 + arow) * 256 + apart;
  const ushortt* pAh1 = Ah_g + (u64)(p0 + arow + 64) * 256 + apart;
  const ushortt* pAl0 = Al_g + (u64)(p0 + arow) * 256 + apart;
  const ushortt* pAl1 = Al_g + (u64)(p0 + arow + 64) * 256 + apart;
  const ushortt* pBh  = Bh_g + (u64)(q0 + arow) * 256 + apart;
  const ushortt* pBl  = Bl_g + (u64)(q0 + arow) * 256 + apart;
  float4 rAh0 = *(const float4*)pAh0;
  float4 rAh1 = *(const float4*)pAh1;
  float4 rAl0 = *(const float4*)pAl0;
  float4 rAl1 = *(const float4*)pAl1;
  float4 rBh  = *(const float4*)pBh;
  float4 rBl  = *(const float4*)pBl;
  f32x4 acc[2][4];
  #pragma unroll
  for (int a = 0; a < 2; ++a)
    #pragma unroll
    for (int b = 0; b < 4; ++b)
      #pragma unroll
      for (int e = 0; e < 4; ++e) acc[a][b][e] = 0.0f;
  for (int k0 = 0; k0 < 256; k0 += 32) {
    __syncthreads();
    *(float4*)&As_hi[arow * 32 + apart] = rAh0;
    *(float4*)&As_hi[(arow + 64) * 32 + apart] = rAh1;
    *(float4*)&As_lo[arow * 32 + apart] = rAl0;
    *(float4*)&As_lo[(arow + 64) * 32 + apart] = rAl1;
    *(float4*)&Bs_hi[arow * 32 + apart] = rBh;
    *(float4*)&Bs_lo[arow * 32 + apart] = rBl;
    __syncthreads();
    if (k0 + 32 < 256) {
      rAh0 = *(const float4*)(pAh0 + k0 + 32);
      rAh1 = *(const float4*)(pAh1 + k0 + 32);
      rAl0 = *(const float4*)(pAl0 + k0 + 32);
      rAl1 = *(const float4*)(pAl1 + k0 + 32);
      rBh  = *(const float4*)(pBh + k0 + 32);
      rBl  = *(const float4*)(pBl + k0 + 32);
    }
    bhalf8 Ah[2], Al[2], Bh[4], Bl[4];
    #pragma unroll
    for (int a = 0; a < 2; ++a) {
      int off = (wv * 32 + a * 16 + lr) * 32 + lk * 8;
      Ah[a] = *(const bhalf8*)&As_hi[off];
      Al[a] = *(const bhalf8*)&As_lo[off];
    }
    #pragma unroll
    for (int b = 0; b < 4; ++b) {
      int off = (b * 16 + lr) * 32 + lk * 8;
      Bh[b] = *(const bhalf8*)&Bs_hi[off];
      Bl[b] = *(const bhalf8*)&Bs_lo[off];
    }
    #pragma unroll
    for (int a = 0; a < 2; ++a)
      #pragma unroll
      for (int b = 0; b < 4; ++b) {
        acc[a][b] = __builtin_amdgcn_mfma_f32_16x16x32_bf16(Ah[a], Bh[b], acc[a][b], 0, 0, 0);
        acc[a][b] = __builtin_amdgcn_mfma_f32_16x16x32_bf16(Ah[a], Bl[b], acc[a][b], 0, 0, 0);
        acc[a][b] = __builtin_amdgcn_mfma_f32_16x16x32_bf16(Al[a], Bh[b], acc[a][b], 0, 0, 0);
      }
  }
  #pragma unroll
  for (int a = 0; a < 2; ++a)
    #pragma unroll
    for (int b = 0; b < 4; ++b)
      #pragma unroll
      for (int r = 0; r < 4; ++r) {
        int p = p0 + wv * 32 + a * 16 + lk * 4 + r;
        int q = q0 + b * 16 + lr;
        G[(u64)p * NPIXP + q] = acc[a][b][r];
      }
}

// ---------------- scoremax: per-(y,ys) block, register stencil acc, float2 loads --------
// grid(48, 48, 2), block 256. ssq combined from 4 ch-block partials in fixed order.
__launch_bounds__(256)
__global__ void scoremax_kernel(const float* __restrict__ Gb, const float* __restrict__ ssqp,
                                u64* __restrict__ rmax) {
  int y = blockIdx.x, ys = blockIdx.y, b = blockIdx.z;
  const float* G = Gb + (u64)b * GSZ;
  const float* sq0 = ssqp + (u64)b * 4 * NPIX;
  __shared__ float Gt1[50][52];
  __shared__ float sc[48][52];
  __shared__ float sr[152];
  __shared__ float rkl[48];
  int tid = threadIdx.x;
  float racc[9];
  for (int dy = 0; dy < 3; ++dy) {
    if (dy > 0) __syncthreads();           // prior stencil done before Gt1 overwrite
    for (int t = tid; t < 1250; t += 256) {
      int u = t / 25, v2 = (t - u * 25) * 2;
      float2 g = *(const float2*)&G[(u64)((y + dy) * 50 + u) * NPIXP + (ys + dy) * 50 + v2];
      *(float2*)&Gt1[u][v2] = g;
    }
    if (dy == 0 && tid < 150) {
      int d = tid / 50, v = tid - d * 50;
      int idx2 = (ys + d) * 50 + v;
      sr[d * 50 + v] = ((sq0[idx2] + sq0[NPIX + idx2]) + sq0[2 * NPIX + idx2])
                       + sq0[3 * NPIX + idx2];
    }
    __syncthreads();
    if (dy == 0 && tid < 48) {
      float t = 0.0f;
      #pragma unroll
      for (int d = 0; d < 3; ++d)
        #pragma unroll
        for (int dx = 0; dx < 3; ++dx) t += sr[d * 50 + tid + dx];
      rkl[tid] = 1.0f / sqrtf(t);
    }
    #pragma unroll
    for (int k = 0; k < 9; ++k) {
      int idx = tid + k * 256;
      int x = idx / 48, xs = idx - x * 48;
      float v = Gt1[x][xs] + Gt1[x + 1][xs + 1] + Gt1[x + 2][xs + 2];
      racc[k] = (dy == 0) ? v : racc[k] + v;
    }
  }
  #pragma unroll
  for (int k = 0; k < 9; ++k) {
    int idx = tid + k * 256;
    int x = idx / 48, xs = idx - x * 48;
    sc[x][xs] = racc[k];
  }
  __syncthreads();
  if (tid < 192) {
    int r = tid >> 2, part = tid & 3;
    float best = -1e30f; int bxs = 0;
    #pragma unroll
    for (int i = 0; i < 12; ++i) {
      int xs = part * 12 + i;
      float v = sc[r][xs] * rkl[xs];
      if (v > best) { best = v; bxs = xs; }   // strict >: smallest xs within range
    }
    #pragma unroll
    for (int o = 1; o < 4; o <<= 1) {        // parts have increasing xs; ties keep smaller
      float ov = __shfl_down(best, o);
      int oi = __shfl_down(bxs, o);
      if (ov > best || (ov == best && oi < bxs)) { best = ov; bxs = oi; }
    }
    if (part == 0) {
      int ps = ys * 48 + bxs;
      unsigned ub = __float_as_uint(best);
      unsigned enc = (ub & 0x80000000u) ? ~ub : (ub | 0x80000000u);
      u64 key = ((u64)enc << 32) | (u64)(2303 - ps);
      atomicMax(&rmax[(u64)b * HW + y * 48 + r], key);
    }
  }
}

// ---------------- reassemble: paste chosen patches + overlap normalize ----------------
__global__ void reassemble_kernel(const float* __restrict__ padS_cl, const u64* __restrict__ rmax,
                                  float* __restrict__ rF_cl) {
  int pix = blockIdx.x, b = blockIdx.y;
  int y = pix / 48, x = pix % 48;
  const u64* rm = rmax + (u64)b * HW;
  const float* S = padS_cl + (u64)b * (NPIX * NC);
  int ch = threadIdx.x;
  float sum = 0.0f;
  #pragma unroll
  for (int i = 0; i < 3; ++i)
    #pragma unroll
    for (int j = 0; j < 3; ++j) {
      int yn = y + 1 - i, xn = x + 1 - j;
      if (yn >= 0 && yn < 48 && xn >= 0 && xn < 48) {
        int ps = 2303 - (int)(unsigned)(rm[yn * 48 + xn] & 0xFFFFFFFFu);
        int ys = ps / 48, xs = ps % 48;
        sum += S[((ys + i) * 50 + xs + j) * NC + ch];
      }
    }
  float cy = (y == 0 || y == 47) ? 2.0f : 3.0f;
  float cx = (x == 0 || x == 47) ? 2.0f : 3.0f;
  rF_cl[(u64)b * (HW * NC) + pix * NC + ch] = sum / (cy * cx);
}

// ---------------- coloring: 64x64 tile, 4x4/thread, float4 LDS ----------------
__launch_bounds__(256)
__global__ void coloring_kernel(const float* __restrict__ Yf, const double* __restrict__ snorm,
                                const double* __restrict__ mean, const float* __restrict__ rF_cl,
                                float* __restrict__ out) {
  int b = blockIdx.z;
  const float* A = Yf + (2 + b) * MATSZ;
  const float* Bp = rF_cl + (u64)b * (HW * NC);
  const double* mn = mean + (2 + b) * NC;
  float cscale = (float)sqrt(snorm[2 + b]);
  int m0 = blockIdx.y * 64, n0 = blockIdx.x * 64;
  __shared__ float As[16][68], Bs[16][68];
  int tid = threadIdx.x;
  int tx = tid & 15, ty = tid >> 4;
  int li = tid >> 2, lk4 = tid & 3;
  int pix = tid >> 2, kq = (tid & 3) * 4;
  float acc[4][4] = {};
  for (int kc = 0; kc < 256; kc += 16) {
    __syncthreads();
    float4 va = *(const float4*)&A[(u64)(m0 + li) * NC + kc + lk4 * 4];
    As[lk4 * 4 + 0][li] = va.x; As[lk4 * 4 + 1][li] = va.y;
    As[lk4 * 4 + 2][li] = va.z; As[lk4 * 4 + 3][li] = va.w;
    float4 vb = *(const float4*)&Bp[(u64)(n0 + pix) * NC + kc + kq];
    Bs[kq + 0][pix] = vb.x; Bs[kq + 1][pix] = vb.y;
    Bs[kq + 2][pix] = vb.z; Bs[kq + 3][pix] = vb.w;
    __syncthreads();
    #pragma unroll
    for (int kk = 0; kk < 16; ++kk) {
      float4 a = *(const float4*)&As[kk][ty * 4];
      float4 b2 = *(const float4*)&Bs[kk][tx * 4];
      float av[4] = {a.x, a.y, a.z, a.w};
      float bv[4] = {b2.x, b2.y, b2.z, b2.w};
      #pragma unroll
      for (int i = 0; i < 4; ++i)
        #pragma unroll
        for (int j = 0; j < 4; ++j) acc[i][j] += av[i] * bv[j];
    }
  }
  #pragma unroll
  for (int i = 0; i < 4; ++i) {
    int row = m0 + ty * 4 + i;
    float madd = (float)mn[row];
    float4 v = make_float4(acc[i][0] * cscale + madd, acc[i][1] * cscale + madd,
                           acc[i][2] * cscale + madd, acc[i][3] * cscale + madd);
    *(float4*)&out[(u64)b * (NC * HW) + (u64)row * HW + n0 + tx * 4] = v;
  }
}

// ---------------- host ----------------
extern "C" void kernel_launch(void* const* d_in, const int* in_sizes, int n_in,
                              void* d_out, int out_size, void* d_ws, size_t ws_size,
                              hipStream_t stream) {
  const float* c = (const float*)d_in[0];
  const float* s = (const float*)d_in[1];
  float* out = (float*)d_out;

  char* ws = (char*)d_ws;
  size_t off = 0;
  auto alloc = [&](size_t bytes) {
    void* p = ws + off;
    off = (off + bytes + 255) & ~(size_t)255;
    return p;
  };
  double* mean   = (double*)alloc(4 * NC * sizeof(double));
  float* covp    = (float*)alloc((size_t)4 * NSLAB * MATSZ * sizeof(float));
  float* Ya      = (float*)alloc((size_t)4 * MATSZ * sizeof(float));
  float* Yb      = (float*)alloc((size_t)4 * MATSZ * sizeof(float));
  float* Za      = (float*)alloc((size_t)4 * MATSZ * sizeof(float));
  float* Zb      = (float*)alloc((size_t)4 * MATSZ * sizeof(float));
  float* T       = (float*)alloc((size_t)4 * MATSZ * sizeof(float));
  // memset group A: padS_cl + 4 bf16 buffers (contiguous)
  size_t offA = off;
  float* padS_cl = (float*)alloc((size_t)2 * NPIX * NC * sizeof(float));
  ushortt* padCk_hi = (ushortt*)alloc((size_t)2 * PMSZ * sizeof(ushortt));
  ushortt* padCk_lo = (ushortt*)alloc((size_t)2 * PMSZ * sizeof(ushortt));
  ushortt* padSk_hi = (ushortt*)alloc((size_t)2 * PMSZ * sizeof(ushortt));
  ushortt* padSk_lo = (ushortt*)alloc((size_t)2 * PMSZ * sizeof(ushortt));
  size_t lenA = off - offA;
  float* rF_cl   = (float*)alloc((size_t)2 * HW * NC * sizeof(float));
  float* G       = (float*)alloc((size_t)2 * GSZ * sizeof(float));
  // memset group B: rmax + snorm + ssqp (contiguous)
  size_t offB = off;
  u64*   rmax    = (u64*)alloc((size_t)2 * HW * sizeof(u64));
  double* snorm  = (double*)alloc(4 * sizeof(double));
  float* ssqp    = (float*)alloc((size_t)2 * 4 * NPIX * sizeof(float));
  size_t lenB = off - offB;

  hipMemsetAsync(ws + offA, 0, lenA, stream);
  hipMemsetAsync(ws + offB, 0, lenB, stream);

  mean_kernel<<<dim3(256, 4), 64, 0, stream>>>(c, s, mean, snorm);
  cov_part<<<dim3(4, 4, 4 * NSLAB), dim3(16, 16), 0, stream>>>(c, s, covp);
  cov_reduce<<<dim3(256, 4), 256, 0, stream>>>(covp, mean, snorm, Ya, Za);
  ns_gemm_Y<<<dim3(8, 8, 4), dim3(16, 16), 0, stream>>>(Ya, Za, Yb);  // Y1 = Y0*T0

  float *Yc = Yb, *Zc = Za, *Yn = Ya, *Zn = Zb;
  for (int it = 1; it < NS_ITERS; ++it) {
    ns_gemm_T<<<dim3(8, 8, 4), dim3(16, 16), 0, stream>>>(Zc, Yc, T);
    ns_gemm_YZ<<<dim3(8, 8, 8), dim3(16, 16), 0, stream>>>(Yc, Zc, T, Yn, Zn);
    float* t1 = Yc; Yc = Yn; Yn = t1;
    float* t2 = Zc; Zc = Zn; Zn = t2;
  }

  whiten_kernel<<<dim3(36, 4, 4), 256, 0, stream>>>(c, s, Zc, snorm, mean,
                                                    padCk_hi, padCk_lo, padSk_hi, padSk_lo,
                                                    padS_cl, ssqp);

  gram_mfma<<<dim3(20, 40, 2), 256, 0, stream>>>(padCk_hi, padCk_lo, padSk_hi, padSk_lo, G);
  scoremax_kernel<<<dim3(48, 48, 2), 256, 0, stream>>>(G, ssqp, rmax);

  reassemble_kernel<<<dim3(2304, 2), 256, 0, stream>>>(padS_cl, rmax, rF_cl);
  coloring_kernel<<<dim3(36, 4, 2), 256, 0, stream>>>(Yc, snorm, mean, rF_cl, out);
}